// Round 14
// baseline (633.098 us; speedup 1.0000x reference)
//
#include <hip/hip_runtime.h>

#define N_NODES 100000
#define N_EDGES 3200000
#define N_GRAPHS 5000
#define BN_EPS 1e-5f
#define HPAD 80        // hidden 75 padded to 80
#define CHUNK 4096     // edges per bucket-sort block
#define NBLKA 782      // ceil(N_EDGES / CHUNK)
#define NBKT 196       // buckets of 512 nodes (dst >> 9)
#define NPAD2 (NBKT * 512)   // 100352
#define NS1 599        // ceil(NBKT*NBLKA / 256)
#define LALLOC (NS1 * 256)
#define VPT 3          // ceil(NS1 / 256) for ks2

// ---------- node encoder: h = x @ node_w + node_b ----------
__global__ void k_encode(const float* __restrict__ x, const float* __restrict__ W,
                         const float* __restrict__ b, float* __restrict__ h) {
    __shared__ float sW[448];
    __shared__ float sb[32];
    for (int i = threadIdx.x; i < 448; i += 256) sW[i] = W[i];
    if (threadIdx.x < 32) sb[threadIdx.x] = b[threadIdx.x];
    __syncthreads();
    int n = blockIdx.x * 256 + threadIdx.x;
    if (n >= N_NODES) return;
    float xi[14];
#pragma unroll
    for (int k = 0; k < 14; k++) xi[k] = x[n * 14 + k];
    float4* hp = (float4*)(h + (size_t)n * 32);
#pragma unroll
    for (int q = 0; q < 8; q++) {
        float4 acc;
        float* ap = (float*)&acc;
#pragma unroll
        for (int i = 0; i < 4; i++) {
            int c = q * 4 + i;
            float a = sb[c];
#pragma unroll
            for (int k = 0; k < 14; k++) a += xi[k] * sW[k * 32 + c];
            ap[i] = a;
        }
        hp[q] = acc;
    }
}

// ---------- weight prep ----------
__global__ void k_prep(const float* __restrict__ W1, const float* __restrict__ b1,
                       const float* __restrict__ W2,
                       float* __restrict__ w1tp, float* __restrict__ b1p,
                       float* __restrict__ w2p) {
    int i = blockIdx.x * 256 + threadIdx.x;
    if (i < 2 * HPAD * 32) {
        int l = i / (HPAD * 32), r = i % (HPAD * 32);
        int j = r / 32, c = r % 32;
        w1tp[i] = (j < 75) ? W1[l * 2400 + c * 75 + j] : 0.f;
        w2p[i]  = (j < 75) ? W2[l * 2400 + j * 32 + c] : 0.f;
    } else if (i < 2 * HPAD * 32 + 2 * HPAD) {
        int k = i - 2 * HPAD * 32;
        int l = k / HPAD, j = k % HPAD;
        b1p[k] = (j < 75) ? b1[l * 75 + j] : 0.f;
    }
}

// ---------- bucket sort phase A: 196-bucket per-block histogram ----------
__global__ void __launch_bounds__(256) ksA(const int* __restrict__ ei, int* __restrict__ cmat) {
    __shared__ int lh[NBKT];
    if (threadIdx.x < NBKT) lh[threadIdx.x] = 0;
    __syncthreads();
    int b0 = blockIdx.x * CHUNK;
    for (int i = threadIdx.x; i < CHUNK; i += 256) {
        int e = b0 + i;
        if (e < N_EDGES) atomicAdd(&lh[ei[N_EDGES + e] >> 9], 1);
    }
    __syncthreads();
    if (threadIdx.x < NBKT) cmat[threadIdx.x * NBLKA + blockIdx.x] = lh[threadIdx.x];
}

// ---------- parallel exclusive scan of cmat ----------
__global__ void ks1(const int* __restrict__ a, int* __restrict__ bs) {
    __shared__ int s[256];
    int i = blockIdx.x * 256 + threadIdx.x;
    s[threadIdx.x] = a[i];
    __syncthreads();
    for (int o = 128; o > 0; o >>= 1) {
        if (threadIdx.x < o) s[threadIdx.x] += s[threadIdx.x + o];
        __syncthreads();
    }
    if (threadIdx.x == 0) bs[blockIdx.x] = s[0];
}

__global__ void ks2(int* __restrict__ bs) {
    __shared__ int s[256];
    int t = threadIdx.x;
    int v[VPT];
    int base = t * VPT, sum = 0;
#pragma unroll
    for (int k = 0; k < VPT; k++) {
        int idx = base + k;
        int x = (idx < NS1) ? bs[idx] : 0;
        v[k] = sum; sum += x;
    }
    s[t] = sum;
    __syncthreads();
    for (int o = 1; o < 256; o <<= 1) {
        int add = (t >= o) ? s[t - o] : 0;
        __syncthreads();
        s[t] += add;
        __syncthreads();
    }
    int excl = (t == 0) ? 0 : s[t - 1];
#pragma unroll
    for (int k = 0; k < VPT; k++) {
        int idx = base + k;
        if (idx < NS1) bs[idx] = excl + v[k];
    }
}

__global__ void ks3(int* __restrict__ a, const int* __restrict__ bs) {
    __shared__ int s[256];
    int t = threadIdx.x, i = blockIdx.x * 256 + t;
    int v = a[i];
    s[t] = v;
    __syncthreads();
    for (int o = 1; o < 256; o <<= 1) {
        int add = (t >= o) ? s[t - o] : 0;
        __syncthreads();
        s[t] += add;
        __syncthreads();
    }
    a[i] = s[t] - v + bs[blockIdx.x];
}

// ---------- phase B: scatter records into 196-bucket-grouped buf1 ----------
__global__ void __launch_bounds__(256) ksB(const int* __restrict__ ei, const float* __restrict__ ea,
                                           const int* __restrict__ cmat, float4* __restrict__ buf1) {
    __shared__ int base[NBKT];
    if (threadIdx.x < NBKT) base[threadIdx.x] = cmat[threadIdx.x * NBLKA + blockIdx.x];
    __syncthreads();
    int b0 = blockIdx.x * CHUNK;
    for (int i = threadIdx.x; i < CHUNK; i += 256) {
        int e = b0 + i;
        if (e >= N_EDGES) break;
        int src = ei[e], dst = ei[N_EDGES + e];
        float a0 = ea[(size_t)e * 3 + 0], a1 = ea[(size_t)e * 3 + 1], a2 = ea[(size_t)e * 3 + 2];
        int pos = atomicAdd(&base[dst >> 9], 1);
        buf1[pos] = make_float4(a0, a1, a2, __int_as_float(src | ((dst & 511) << 17)));
    }
}

// ---------- phase C: per-512-node-bucket exact CSR (1024-thread blocks) ----------
__global__ void __launch_bounds__(1024) ksC(const int* __restrict__ cmat, const float4* __restrict__ buf1,
                                            float4* __restrict__ packed, int* __restrict__ offs) {
    __shared__ int cnt[512];
    __shared__ int sc[512];
    __shared__ int excl[513];
    int g = blockIdx.x, t = threadIdx.x;
    int bb = cmat[g * NBLKA];
    int be = (g == NBKT - 1) ? N_EDGES : cmat[(g + 1) * NBLKA];
    if (t < 512) cnt[t] = 0;
    __syncthreads();
    for (int j = bb + t; j < be; j += 1024) {
        int bits = __float_as_int(buf1[j].w);
        atomicAdd(&cnt[bits >> 17], 1);
    }
    __syncthreads();
    if (t < 512) sc[t] = cnt[t];
    __syncthreads();
    for (int o = 1; o < 512; o <<= 1) {
        int add = 0;
        if (t < 512 && t >= o) add = sc[t - o];
        __syncthreads();
        if (t < 512) sc[t] += add;
        __syncthreads();
    }
    if (t < 512) excl[t] = sc[t] - cnt[t];
    if (t == 511) excl[512] = sc[511];
    __syncthreads();
    if (t < 512) offs[g * 512 + t] = bb + excl[t];
    if (g == NBKT - 1 && t == 0) offs[NPAD2] = N_EDGES;
    if (t < 512) cnt[t] = 0;
    __syncthreads();
    for (int j = bb + t; j < be; j += 1024) {
        float4 r = buf1[j];
        int bits = __float_as_int(r.w);
        int dl = bits >> 17, src = bits & 0x1FFFF;
        int rank = atomicAdd(&cnt[dl], 1);
        packed[bb + excl[dl] + rank] = make_float4(r.x, r.y, r.z, __int_as_float(src));
    }
}

// ---------- pull aggregation: 32 threads/node, 4-deep software pipeline ----------
__global__ void __launch_bounds__(256) k_agg(const float4* __restrict__ packed,
                                             const int* __restrict__ offs,
                                             const float* __restrict__ eW, const float* __restrict__ eb,
                                             const float* __restrict__ h, float* __restrict__ agg) {
    int t = blockIdx.x * 256 + threadIdx.x;   // N_NODES*32 exact
    int n = t >> 5, s = t & 31;
    int q = s & 7, part = s >> 3;             // quad 0..7, edge-part 0..3
    int c0 = q * 4;
    float w0[4], w1[4], w2[4], bb4[4];
#pragma unroll
    for (int i = 0; i < 4; i++) {
        w0[i] = eW[c0 + i];
        w1[i] = eW[32 + c0 + i];
        w2[i] = eW[64 + c0 + i];
        bb4[i] = eb[c0 + i];
    }
    int beg = offs[n], end = offs[n + 1];
    float acc0[4] = {0.f, 0.f, 0.f, 0.f};
    float acc1[4] = {0.f, 0.f, 0.f, 0.f};
    float acc2[4] = {0.f, 0.f, 0.f, 0.f};
    float acc3[4] = {0.f, 0.f, 0.f, 0.f};
    int j = beg + part;
    // depth-4: 4 independent packed loads, then 4 dependent h-gathers, then FMAs
    for (; j + 12 < end; j += 16) {
        float4 pa = packed[j];
        float4 pb = packed[j + 4];
        float4 pc = packed[j + 8];
        float4 pd = packed[j + 12];
        float4 ha = *(const float4*)(h + (size_t)__float_as_int(pa.w) * 32 + c0);
        float4 hb = *(const float4*)(h + (size_t)__float_as_int(pb.w) * 32 + c0);
        float4 hc = *(const float4*)(h + (size_t)__float_as_int(pc.w) * 32 + c0);
        float4 hd = *(const float4*)(h + (size_t)__float_as_int(pd.w) * 32 + c0);
        const float* hap = (const float*)&ha;
        const float* hbp = (const float*)&hb;
        const float* hcp = (const float*)&hc;
        const float* hdp = (const float*)&hd;
#pragma unroll
        for (int i = 0; i < 4; i++) {
            acc0[i] += fmaxf(hap[i] + pa.x * w0[i] + pa.y * w1[i] + pa.z * w2[i] + bb4[i], 0.f);
            acc1[i] += fmaxf(hbp[i] + pb.x * w0[i] + pb.y * w1[i] + pb.z * w2[i] + bb4[i], 0.f);
            acc2[i] += fmaxf(hcp[i] + pc.x * w0[i] + pc.y * w1[i] + pc.z * w2[i] + bb4[i], 0.f);
            acc3[i] += fmaxf(hdp[i] + pd.x * w0[i] + pd.y * w1[i] + pd.z * w2[i] + bb4[i], 0.f);
        }
    }
    // depth-2 remainder
    for (; j + 4 < end; j += 8) {
        float4 pa = packed[j];
        float4 pb = packed[j + 4];
        float4 ha = *(const float4*)(h + (size_t)__float_as_int(pa.w) * 32 + c0);
        float4 hb = *(const float4*)(h + (size_t)__float_as_int(pb.w) * 32 + c0);
        const float* hap = (const float*)&ha;
        const float* hbp = (const float*)&hb;
#pragma unroll
        for (int i = 0; i < 4; i++) {
            acc0[i] += fmaxf(hap[i] + pa.x * w0[i] + pa.y * w1[i] + pa.z * w2[i] + bb4[i], 0.f);
            acc1[i] += fmaxf(hbp[i] + pb.x * w0[i] + pb.y * w1[i] + pb.z * w2[i] + bb4[i], 0.f);
        }
    }
    // depth-1 remainder
    if (j < end) {
        float4 p = packed[j];
        float4 hs = *(const float4*)(h + (size_t)__float_as_int(p.w) * 32 + c0);
        const float* hp = (const float*)&hs;
#pragma unroll
        for (int i = 0; i < 4; i++)
            acc0[i] += fmaxf(hp[i] + p.x * w0[i] + p.y * w1[i] + p.z * w2[i] + bb4[i], 0.f);
    }
    float acc[4];
#pragma unroll
    for (int i = 0; i < 4; i++) {
        acc[i] = (acc0[i] + acc1[i]) + (acc2[i] + acc3[i]);
        acc[i] += __shfl_xor(acc[i], 8, 64);
        acc[i] += __shfl_xor(acc[i], 16, 64);
    }
    if (part == 0)
        *(float4*)(agg + (size_t)n * 32 + c0) = make_float4(acc[0], acc[1], acc[2], acc[3]);
}

// ---------- fused MLP: z = relu((h+agg)@W1+b1)@W2+b2, written over agg ----------
__global__ void __launch_bounds__(256, 4) k_mlp(const float* __restrict__ h, float* __restrict__ agg,
                                                const float* __restrict__ W1, const float* __restrict__ B1,
                                                const float* __restrict__ W2, const float* __restrict__ b2) {
    __shared__ float hidL[32 * 84];    // 4 waves * 8 nodes; stride 84
    unsigned t = blockIdx.x * 256 + threadIdx.x;   // N_NODES*8 exact
    unsigned lane = threadIdx.x & 63;
    unsigned wv = threadIdx.x >> 6;
    unsigned oct = lane >> 3;
    unsigned nd = lane & 7;
    unsigned n = (t >> 6) * 8 + nd;
    const float4* hp = (const float4*)(h + (size_t)n * 32);
    const float4* ap = (const float4*)(agg + (size_t)n * 32);
    float zc[32];
#pragma unroll
    for (int q = 0; q < 8; q++) {
        float4 hv = hp[q], av = ap[q];
        zc[q * 4 + 0] = hv.x + av.x;
        zc[q * 4 + 1] = hv.y + av.y;
        zc[q * 4 + 2] = hv.z + av.z;
        zc[q * 4 + 3] = hv.w + av.w;
    }
    float hid[10];
#pragma unroll
    for (int i = 0; i < 10; i++) {
        int j = (int)oct * 10 + i;
        const float4* wp = (const float4*)(W1 + j * 32);
        float a0 = 0.f, a1 = 0.f, a2 = 0.f, a3 = 0.f;
#pragma unroll
        for (int q = 0; q < 8; q++) {
            float4 wv4 = wp[q];
            a0 += zc[q * 4 + 0] * wv4.x;
            a1 += zc[q * 4 + 1] * wv4.y;
            a2 += zc[q * 4 + 2] * wv4.z;
            a3 += zc[q * 4 + 3] * wv4.w;
        }
        hid[i] = fmaxf(B1[j] + ((a0 + a1) + (a2 + a3)), 0.f);
    }
    float* hrow = &hidL[(wv * 8 + nd) * 84];
#pragma unroll
    for (int i = 0; i < 10; i++) hrow[oct * 10 + i] = hid[i];
    float4 zo = *(const float4*)(b2 + oct * 4);
    const float4* hv4 = (const float4*)hrow;
#pragma unroll
    for (int k = 0; k < 20; k++) {
        float4 hv = hv4[k];
        const float* wr = W2 + (k * 4) * 32 + oct * 4;
        float4 wa = *(const float4*)(wr);
        float4 wb = *(const float4*)(wr + 32);
        float4 wc = *(const float4*)(wr + 64);
        float4 wd = *(const float4*)(wr + 96);
        zo.x += hv.x * wa.x + hv.y * wb.x + hv.z * wc.x + hv.w * wd.x;
        zo.y += hv.x * wa.y + hv.y * wb.y + hv.z * wc.y + hv.w * wd.y;
        zo.z += hv.x * wa.z + hv.y * wb.z + hv.z * wc.z + hv.w * wd.z;
        zo.w += hv.x * wa.w + hv.y * wb.w + hv.z * wc.w + hv.w * wd.w;
    }
    *(float4*)(agg + (size_t)n * 32 + oct * 4) = zo;
}

// ---------- BN stats ----------
__global__ void __launch_bounds__(256) k_stats(const float* __restrict__ z, float* __restrict__ stats) {
    __shared__ float ls[4 * 64];
    int tid = threadIdx.x;
    int c = tid & 31;
    float s = 0.f, s2 = 0.f;
    for (int e = blockIdx.x * 256 + tid; e < N_NODES * 32; e += 256 * 256) {
        float v = z[e];
        s += v; s2 += v * v;
    }
    s += __shfl_down(s, 32, 64);
    s2 += __shfl_down(s2, 32, 64);
    int wave = tid >> 6, lane = tid & 63;
    if (lane < 32) { ls[wave * 64 + c] = s; ls[wave * 64 + 32 + c] = s2; }
    __syncthreads();
    if (tid < 64) {
        float a = ls[tid] + ls[64 + tid] + ls[128 + tid] + ls[192 + tid];
        atomicAdd(&stats[tid], a);
    }
}

// ---------- BN apply + relu ----------
__global__ void k_bn(const float* __restrict__ z, float* __restrict__ h,
                     const float* __restrict__ stats, const float* __restrict__ g,
                     const float* __restrict__ b) {
    int t = blockIdx.x * 256 + threadIdx.x;
    if (t >= N_NODES * 8) return;
    int q = t & 7;
    float4 zv = ((const float4*)z)[t];
    float* zp = (float*)&zv;
    float4 ov;
    float* op = (float*)&ov;
    const float invN = 1.0f / (float)N_NODES;
#pragma unroll
    for (int i = 0; i < 4; i++) {
        int c = q * 4 + i;
        float mu = stats[c] * invN;
        float var = stats[32 + c] * invN - mu * mu;
        float sc = g[c] / sqrtf(var + BN_EPS);
        op[i] = fmaxf((zp[i] - mu) * sc + b[c], 0.f);
    }
    ((float4*)h)[t] = ov;
}

// ---------- graph offsets (batch is sorted) ----------
__global__ void k_goff(const int* __restrict__ batch, int* __restrict__ goff) {
    int g = blockIdx.x * 256 + threadIdx.x;
    if (g > N_GRAPHS) return;
    int lo = 0, hi = N_NODES;
    while (lo < hi) {
        int mid = (lo + hi) >> 1;
        if (batch[mid] < g) lo = mid + 1; else hi = mid;
    }
    goff[g] = lo;
}

// ---------- mean-pool: one wave per graph ----------
__global__ void __launch_bounds__(256) k_pool2(const float* __restrict__ h, const int* __restrict__ goff,
                                               float* __restrict__ gsum) {
    int wid = threadIdx.x >> 6, lane = threadIdx.x & 63;
    int g = blockIdx.x * 4 + wid;
    if (g >= N_GRAPHS) return;
    int s = goff[g], e = goff[g + 1];
    int c = lane & 31, half = lane >> 5;
    float acc = 0.f;
    for (int n = s + half; n < e; n += 2) acc += h[(size_t)n * 32 + c];
    acc += __shfl_down(acc, 32, 64);
    if (lane < 32) gsum[(size_t)g * 32 + c] = acc;
}

__global__ void k_head(const float* __restrict__ gsum, const int* __restrict__ goff,
                       const float* __restrict__ W1, const float* __restrict__ b1,
                       const float* __restrict__ W2, const float* __restrict__ b2,
                       float* __restrict__ out) {
    __shared__ float sW1[512], sb1[16], sW2[32], sb2[2];
    for (int i = threadIdx.x; i < 512; i += 256) sW1[i] = W1[i];
    if (threadIdx.x < 16) sb1[threadIdx.x] = b1[threadIdx.x];
    if (threadIdx.x < 32) sW2[threadIdx.x] = W2[threadIdx.x];
    if (threadIdx.x < 2) sb2[threadIdx.x] = b2[threadIdx.x];
    __syncthreads();
    int gI = blockIdx.x * 256 + threadIdx.x;
    if (gI >= N_GRAPHS) return;
    float cnt = (float)(goff[gI + 1] - goff[gI]);
    float inv = 1.0f / fmaxf(cnt, 1.0f);
    float gx[32];
#pragma unroll
    for (int c = 0; c < 32; c++) gx[c] = gsum[(size_t)gI * 32 + c] * inv;
    float hid[16];
#pragma unroll
    for (int j = 0; j < 16; j++) {
        float a = sb1[j];
#pragma unroll
        for (int c = 0; c < 32; c++) a += gx[c] * sW1[c * 16 + j];
        hid[j] = fmaxf(a, 0.f);
    }
#pragma unroll
    for (int o = 0; o < 2; o++) {
        float a = sb2[o];
#pragma unroll
        for (int j = 0; j < 16; j++) a += hid[j] * sW2[j * 2 + o];
        out[(size_t)gI * 2 + o] = a;
    }
}

extern "C" void kernel_launch(void* const* d_in, const int* in_sizes, int n_in,
                              void* d_out, int out_size, void* d_ws, size_t ws_size,
                              hipStream_t stream) {
    const float* x       = (const float*)d_in[0];
    const int*   ei      = (const int*)d_in[1];
    const float* eattr   = (const float*)d_in[2];
    const int*   batch   = (const int*)d_in[3];
    const float* node_w  = (const float*)d_in[4];
    const float* node_b  = (const float*)d_in[5];
    const float* edge_w  = (const float*)d_in[6];
    const float* edge_b  = (const float*)d_in[7];
    const float* conv_w1 = (const float*)d_in[8];
    const float* conv_b1 = (const float*)d_in[9];
    const float* conv_w2 = (const float*)d_in[10];
    const float* conv_b2 = (const float*)d_in[11];
    const float* bn_g    = (const float*)d_in[12];
    const float* bn_b    = (const float*)d_in[13];
    const float* lin1_w  = (const float*)d_in[14];
    const float* lin1_b  = (const float*)d_in[15];
    const float* lin2_w  = (const float*)d_in[16];
    const float* lin2_b  = (const float*)d_in[17];
    float* out = (float*)d_out;

    float4* packed = (float4*)d_ws;                        // 51.2 MB
    float4* buf1   = packed + N_EDGES;                     // 51.2 MB (CSR build only)
    float*  h      = (float*)(buf1 + N_EDGES);             // 12.8 MB
    float*  agg    = h + (size_t)N_NODES * 32;             // 12.8 MB (z in-place)
    int*    cmat   = (int*)(agg + (size_t)N_NODES * 32);   // LALLOC ints
    int*    t1     = cmat + LALLOC;                        // 768
    int*    offs   = t1 + 768;                             // NPAD2+1
    int*    goff   = offs + NPAD2 + 1;                     // N_GRAPHS+1
    float*  stats  = (float*)(goff + N_GRAPHS + 1);        // 64
    float*  gsum   = stats + 64;                           // G*32
    float*  w1tp   = gsum + (size_t)N_GRAPHS * 32;         // 2*80*32
    float*  b1p    = w1tp + 2 * HPAD * 32;                 // 2*80
    float*  w2p    = b1p + 2 * HPAD;                       // 2*80*32

    int nb_nodes = (N_NODES + 255) / 256;
    int nb_vec   = (N_NODES * 8 + 255) / 256;

    hipMemsetAsync(cmat, 0, LALLOC * sizeof(int), stream);
    k_encode<<<nb_nodes, 256, 0, stream>>>(x, node_w, node_b, h);
    k_prep<<<(2 * HPAD * 32 + 2 * HPAD + 255) / 256, 256, 0, stream>>>(
        conv_w1, conv_b1, conv_w2, w1tp, b1p, w2p);
    k_goff<<<(N_GRAPHS + 1 + 255) / 256, 256, 0, stream>>>(batch, goff);

    ksA<<<NBLKA, 256, 0, stream>>>(ei, cmat);
    ks1<<<NS1, 256, 0, stream>>>(cmat, t1);
    ks2<<<1, 256, 0, stream>>>(t1);
    ks3<<<NS1, 256, 0, stream>>>(cmat, t1);
    ksB<<<NBLKA, 256, 0, stream>>>(ei, eattr, cmat, buf1);
    ksC<<<NBKT, 1024, 0, stream>>>(cmat, buf1, packed, offs);

    for (int l = 0; l < 2; l++) {
        hipMemsetAsync(stats, 0, 64 * sizeof(float), stream);
        k_agg<<<N_NODES * 32 / 256, 256, 0, stream>>>(packed, offs, edge_w, edge_b, h, agg);
        k_mlp<<<N_NODES * 8 / 256, 256, 0, stream>>>(h, agg, w1tp + l * HPAD * 32,
                                                     b1p + l * HPAD, w2p + l * HPAD * 32,
                                                     conv_b2 + l * 32);
        k_stats<<<256, 256, 0, stream>>>(agg, stats);
        k_bn<<<nb_vec, 256, 0, stream>>>(agg, h, stats, bn_g + l * 32, bn_b + l * 32);
    }
    k_pool2<<<(N_GRAPHS + 3) / 4, 256, 0, stream>>>(h, goff, gsum);
    k_head<<<(N_GRAPHS + 255) / 256, 256, 0, stream>>>(gsum, goff, lin1_w, lin1_b, lin2_w, lin2_b, out);
}

// Round 15
// 614.111 us; speedup vs baseline: 1.0309x; 1.0309x over previous
//
#include <hip/hip_runtime.h>
#include <hip/hip_fp16.h>

#define N_NODES 100000
#define N_EDGES 3200000
#define N_GRAPHS 5000
#define BN_EPS 1e-5f
#define HPAD 80        // hidden 75 padded to 80
#define CHUNK 4096     // edges per bucket-sort block
#define NBLKA 782      // ceil(N_EDGES / CHUNK)
#define NBKT 196       // buckets of 512 nodes (dst >> 9)
#define NPAD2 (NBKT * 512)   // 100352
#define NS1 599        // ceil(NBKT*NBLKA / 256)
#define LALLOC (NS1 * 256)
#define VPT 3          // ceil(NS1 / 256) for ks2

// ---------- node encoder: h = x @ node_w + node_b (fp32 + fp16 mirror) ----------
__global__ void k_encode(const float* __restrict__ x, const float* __restrict__ W,
                         const float* __restrict__ b, float* __restrict__ h,
                         __half* __restrict__ h16) {
    __shared__ float sW[448];
    __shared__ float sb[32];
    for (int i = threadIdx.x; i < 448; i += 256) sW[i] = W[i];
    if (threadIdx.x < 32) sb[threadIdx.x] = b[threadIdx.x];
    __syncthreads();
    int n = blockIdx.x * 256 + threadIdx.x;
    if (n >= N_NODES) return;
    float xi[14];
#pragma unroll
    for (int k = 0; k < 14; k++) xi[k] = x[n * 14 + k];
    float4* hp = (float4*)(h + (size_t)n * 32);
    __half2* hq = (__half2*)(h16 + (size_t)n * 32);
#pragma unroll
    for (int q = 0; q < 8; q++) {
        float4 acc;
        float* ap = (float*)&acc;
#pragma unroll
        for (int i = 0; i < 4; i++) {
            int c = q * 4 + i;
            float a = sb[c];
#pragma unroll
            for (int k = 0; k < 14; k++) a += xi[k] * sW[k * 32 + c];
            ap[i] = a;
        }
        hp[q] = acc;
        hq[q * 2 + 0] = __floats2half2_rn(acc.x, acc.y);
        hq[q * 2 + 1] = __floats2half2_rn(acc.z, acc.w);
    }
}

// ---------- weight prep ----------
__global__ void k_prep(const float* __restrict__ W1, const float* __restrict__ b1,
                       const float* __restrict__ W2,
                       float* __restrict__ w1tp, float* __restrict__ b1p,
                       float* __restrict__ w2p) {
    int i = blockIdx.x * 256 + threadIdx.x;
    if (i < 2 * HPAD * 32) {
        int l = i / (HPAD * 32), r = i % (HPAD * 32);
        int j = r / 32, c = r % 32;
        w1tp[i] = (j < 75) ? W1[l * 2400 + c * 75 + j] : 0.f;
        w2p[i]  = (j < 75) ? W2[l * 2400 + j * 32 + c] : 0.f;
    } else if (i < 2 * HPAD * 32 + 2 * HPAD) {
        int k = i - 2 * HPAD * 32;
        int l = k / HPAD, j = k % HPAD;
        b1p[k] = (j < 75) ? b1[l * 75 + j] : 0.f;
    }
}

// ---------- bucket sort phase A: 196-bucket per-block histogram ----------
__global__ void __launch_bounds__(256) ksA(const int* __restrict__ ei, int* __restrict__ cmat) {
    __shared__ int lh[NBKT];
    if (threadIdx.x < NBKT) lh[threadIdx.x] = 0;
    __syncthreads();
    int b0 = blockIdx.x * CHUNK;
    for (int i = threadIdx.x; i < CHUNK; i += 256) {
        int e = b0 + i;
        if (e < N_EDGES) atomicAdd(&lh[ei[N_EDGES + e] >> 9], 1);
    }
    __syncthreads();
    if (threadIdx.x < NBKT) cmat[threadIdx.x * NBLKA + blockIdx.x] = lh[threadIdx.x];
}

// ---------- parallel exclusive scan of cmat ----------
__global__ void ks1(const int* __restrict__ a, int* __restrict__ bs) {
    __shared__ int s[256];
    int i = blockIdx.x * 256 + threadIdx.x;
    s[threadIdx.x] = a[i];
    __syncthreads();
    for (int o = 128; o > 0; o >>= 1) {
        if (threadIdx.x < o) s[threadIdx.x] += s[threadIdx.x + o];
        __syncthreads();
    }
    if (threadIdx.x == 0) bs[blockIdx.x] = s[0];
}

__global__ void ks2(int* __restrict__ bs) {
    __shared__ int s[256];
    int t = threadIdx.x;
    int v[VPT];
    int base = t * VPT, sum = 0;
#pragma unroll
    for (int k = 0; k < VPT; k++) {
        int idx = base + k;
        int x = (idx < NS1) ? bs[idx] : 0;
        v[k] = sum; sum += x;
    }
    s[t] = sum;
    __syncthreads();
    for (int o = 1; o < 256; o <<= 1) {
        int add = (t >= o) ? s[t - o] : 0;
        __syncthreads();
        s[t] += add;
        __syncthreads();
    }
    int excl = (t == 0) ? 0 : s[t - 1];
#pragma unroll
    for (int k = 0; k < VPT; k++) {
        int idx = base + k;
        if (idx < NS1) bs[idx] = excl + v[k];
    }
}

__global__ void ks3(int* __restrict__ a, const int* __restrict__ bs) {
    __shared__ int s[256];
    int t = threadIdx.x, i = blockIdx.x * 256 + t;
    int v = a[i];
    s[t] = v;
    __syncthreads();
    for (int o = 1; o < 256; o <<= 1) {
        int add = (t >= o) ? s[t - o] : 0;
        __syncthreads();
        s[t] += add;
        __syncthreads();
    }
    a[i] = s[t] - v + bs[blockIdx.x];
}

// ---------- phase B: scatter records into 196-bucket-grouped buf1 ----------
__global__ void __launch_bounds__(256) ksB(const int* __restrict__ ei, const float* __restrict__ ea,
                                           const int* __restrict__ cmat, float4* __restrict__ buf1) {
    __shared__ int base[NBKT];
    if (threadIdx.x < NBKT) base[threadIdx.x] = cmat[threadIdx.x * NBLKA + blockIdx.x];
    __syncthreads();
    int b0 = blockIdx.x * CHUNK;
    for (int i = threadIdx.x; i < CHUNK; i += 256) {
        int e = b0 + i;
        if (e >= N_EDGES) break;
        int src = ei[e], dst = ei[N_EDGES + e];
        float a0 = ea[(size_t)e * 3 + 0], a1 = ea[(size_t)e * 3 + 1], a2 = ea[(size_t)e * 3 + 2];
        int pos = atomicAdd(&base[dst >> 9], 1);
        buf1[pos] = make_float4(a0, a1, a2, __int_as_float(src | ((dst & 511) << 17)));
    }
}

// ---------- phase C: per-512-node-bucket exact CSR (1024-thread blocks) ----------
__global__ void __launch_bounds__(1024) ksC(const int* __restrict__ cmat, const float4* __restrict__ buf1,
                                            float4* __restrict__ packed, int* __restrict__ offs) {
    __shared__ int cnt[512];
    __shared__ int sc[512];
    __shared__ int excl[513];
    int g = blockIdx.x, t = threadIdx.x;
    int bb = cmat[g * NBLKA];
    int be = (g == NBKT - 1) ? N_EDGES : cmat[(g + 1) * NBLKA];
    if (t < 512) cnt[t] = 0;
    __syncthreads();
    for (int j = bb + t; j < be; j += 1024) {
        int bits = __float_as_int(buf1[j].w);
        atomicAdd(&cnt[bits >> 17], 1);
    }
    __syncthreads();
    if (t < 512) sc[t] = cnt[t];
    __syncthreads();
    for (int o = 1; o < 512; o <<= 1) {
        int add = 0;
        if (t < 512 && t >= o) add = sc[t - o];
        __syncthreads();
        if (t < 512) sc[t] += add;
        __syncthreads();
    }
    if (t < 512) excl[t] = sc[t] - cnt[t];
    if (t == 511) excl[512] = sc[511];
    __syncthreads();
    if (t < 512) offs[g * 512 + t] = bb + excl[t];
    if (g == NBKT - 1 && t == 0) offs[NPAD2] = N_EDGES;
    if (t < 512) cnt[t] = 0;
    __syncthreads();
    for (int j = bb + t; j < be; j += 1024) {
        float4 r = buf1[j];
        int bits = __float_as_int(r.w);
        int dl = bits >> 17, src = bits & 0x1FFFF;
        int rank = atomicAdd(&cnt[dl], 1);
        packed[bb + excl[dl] + rank] = make_float4(r.x, r.y, r.z, __int_as_float(src));
    }
}

// ---------- pull aggregation: 32 threads/node, fp16 h-gather (half the gather bytes) ----------
__global__ void __launch_bounds__(256) k_agg(const float4* __restrict__ packed,
                                             const int* __restrict__ offs,
                                             const float* __restrict__ eW, const float* __restrict__ eb,
                                             const __half* __restrict__ h16, float* __restrict__ agg) {
    int t = blockIdx.x * 256 + threadIdx.x;   // N_NODES*32 exact
    int n = t >> 5, s = t & 31;
    int q = s & 7, part = s >> 3;             // quad 0..7, edge-part 0..3
    int c0 = q * 4;
    float w0[4], w1[4], w2[4], bb4[4];
#pragma unroll
    for (int i = 0; i < 4; i++) {
        w0[i] = eW[c0 + i];
        w1[i] = eW[32 + c0 + i];
        w2[i] = eW[64 + c0 + i];
        bb4[i] = eb[c0 + i];
    }
    int beg = offs[n], end = offs[n + 1];
    float acc0[4] = {0.f, 0.f, 0.f, 0.f};
    float acc1[4] = {0.f, 0.f, 0.f, 0.f};
    int j = beg + part;
    for (; j + 4 < end; j += 8) {
        float4 pa = packed[j];
        float4 pb = packed[j + 4];
        float2 ra = *(const float2*)(h16 + (size_t)__float_as_int(pa.w) * 32 + c0);
        float2 rb = *(const float2*)(h16 + (size_t)__float_as_int(pb.w) * 32 + c0);
        float2 a01 = __half22float2(*(__half2*)&ra.x);
        float2 a23 = __half22float2(*(__half2*)&ra.y);
        float2 b01 = __half22float2(*(__half2*)&rb.x);
        float2 b23 = __half22float2(*(__half2*)&rb.y);
        float ha4[4] = {a01.x, a01.y, a23.x, a23.y};
        float hb4[4] = {b01.x, b01.y, b23.x, b23.y};
#pragma unroll
        for (int i = 0; i < 4; i++) {
            acc0[i] += fmaxf(ha4[i] + pa.x * w0[i] + pa.y * w1[i] + pa.z * w2[i] + bb4[i], 0.f);
            acc1[i] += fmaxf(hb4[i] + pb.x * w0[i] + pb.y * w1[i] + pb.z * w2[i] + bb4[i], 0.f);
        }
    }
    if (j < end) {
        float4 p = packed[j];
        float2 r = *(const float2*)(h16 + (size_t)__float_as_int(p.w) * 32 + c0);
        float2 a01 = __half22float2(*(__half2*)&r.x);
        float2 a23 = __half22float2(*(__half2*)&r.y);
        float hp4[4] = {a01.x, a01.y, a23.x, a23.y};
#pragma unroll
        for (int i = 0; i < 4; i++)
            acc0[i] += fmaxf(hp4[i] + p.x * w0[i] + p.y * w1[i] + p.z * w2[i] + bb4[i], 0.f);
    }
    float acc[4];
#pragma unroll
    for (int i = 0; i < 4; i++) {
        acc[i] = acc0[i] + acc1[i];
        acc[i] += __shfl_xor(acc[i], 8, 64);
        acc[i] += __shfl_xor(acc[i], 16, 64);
    }
    if (part == 0)
        *(float4*)(agg + (size_t)n * 32 + c0) = make_float4(acc[0], acc[1], acc[2], acc[3]);
}

// ---------- fused MLP: z = relu((h+agg)@W1+b1)@W2+b2, written over agg ----------
__global__ void __launch_bounds__(256, 4) k_mlp(const float* __restrict__ h, float* __restrict__ agg,
                                                const float* __restrict__ W1, const float* __restrict__ B1,
                                                const float* __restrict__ W2, const float* __restrict__ b2) {
    __shared__ float hidL[32 * 84];    // 4 waves * 8 nodes; stride 84
    unsigned t = blockIdx.x * 256 + threadIdx.x;   // N_NODES*8 exact
    unsigned lane = threadIdx.x & 63;
    unsigned wv = threadIdx.x >> 6;
    unsigned oct = lane >> 3;
    unsigned nd = lane & 7;
    unsigned n = (t >> 6) * 8 + nd;
    const float4* hp = (const float4*)(h + (size_t)n * 32);
    const float4* ap = (const float4*)(agg + (size_t)n * 32);
    float zc[32];
#pragma unroll
    for (int q = 0; q < 8; q++) {
        float4 hv = hp[q], av = ap[q];
        zc[q * 4 + 0] = hv.x + av.x;
        zc[q * 4 + 1] = hv.y + av.y;
        zc[q * 4 + 2] = hv.z + av.z;
        zc[q * 4 + 3] = hv.w + av.w;
    }
    float hid[10];
#pragma unroll
    for (int i = 0; i < 10; i++) {
        int j = (int)oct * 10 + i;
        const float4* wp = (const float4*)(W1 + j * 32);
        float a0 = 0.f, a1 = 0.f, a2 = 0.f, a3 = 0.f;
#pragma unroll
        for (int q = 0; q < 8; q++) {
            float4 wv4 = wp[q];
            a0 += zc[q * 4 + 0] * wv4.x;
            a1 += zc[q * 4 + 1] * wv4.y;
            a2 += zc[q * 4 + 2] * wv4.z;
            a3 += zc[q * 4 + 3] * wv4.w;
        }
        hid[i] = fmaxf(B1[j] + ((a0 + a1) + (a2 + a3)), 0.f);
    }
    float* hrow = &hidL[(wv * 8 + nd) * 84];
#pragma unroll
    for (int i = 0; i < 10; i++) hrow[oct * 10 + i] = hid[i];
    float4 zo = *(const float4*)(b2 + oct * 4);
    const float4* hv4 = (const float4*)hrow;
#pragma unroll
    for (int k = 0; k < 20; k++) {
        float4 hv = hv4[k];
        const float* wr = W2 + (k * 4) * 32 + oct * 4;
        float4 wa = *(const float4*)(wr);
        float4 wb = *(const float4*)(wr + 32);
        float4 wc = *(const float4*)(wr + 64);
        float4 wd = *(const float4*)(wr + 96);
        zo.x += hv.x * wa.x + hv.y * wb.x + hv.z * wc.x + hv.w * wd.x;
        zo.y += hv.x * wa.y + hv.y * wb.y + hv.z * wc.y + hv.w * wd.y;
        zo.z += hv.x * wa.z + hv.y * wb.z + hv.z * wc.z + hv.w * wd.z;
        zo.w += hv.x * wa.w + hv.y * wb.w + hv.z * wc.w + hv.w * wd.w;
    }
    *(float4*)(agg + (size_t)n * 32 + oct * 4) = zo;
}

// ---------- BN stats ----------
__global__ void __launch_bounds__(256) k_stats(const float* __restrict__ z, float* __restrict__ stats) {
    __shared__ float ls[4 * 64];
    int tid = threadIdx.x;
    int c = tid & 31;
    float s = 0.f, s2 = 0.f;
    for (int e = blockIdx.x * 256 + tid; e < N_NODES * 32; e += 256 * 256) {
        float v = z[e];
        s += v; s2 += v * v;
    }
    s += __shfl_down(s, 32, 64);
    s2 += __shfl_down(s2, 32, 64);
    int wave = tid >> 6, lane = tid & 63;
    if (lane < 32) { ls[wave * 64 + c] = s; ls[wave * 64 + 32 + c] = s2; }
    __syncthreads();
    if (tid < 64) {
        float a = ls[tid] + ls[64 + tid] + ls[128 + tid] + ls[192 + tid];
        atomicAdd(&stats[tid], a);
    }
}

// ---------- BN apply + relu (fp32 h + fp16 mirror) ----------
__global__ void k_bn(const float* __restrict__ z, float* __restrict__ h,
                     __half* __restrict__ h16,
                     const float* __restrict__ stats, const float* __restrict__ g,
                     const float* __restrict__ b) {
    int t = blockIdx.x * 256 + threadIdx.x;
    if (t >= N_NODES * 8) return;
    int q = t & 7;
    float4 zv = ((const float4*)z)[t];
    float* zp = (float*)&zv;
    float4 ov;
    float* op = (float*)&ov;
    const float invN = 1.0f / (float)N_NODES;
#pragma unroll
    for (int i = 0; i < 4; i++) {
        int c = q * 4 + i;
        float mu = stats[c] * invN;
        float var = stats[32 + c] * invN - mu * mu;
        float sc = g[c] / sqrtf(var + BN_EPS);
        op[i] = fmaxf((zp[i] - mu) * sc + b[c], 0.f);
    }
    ((float4*)h)[t] = ov;
    __half2 p0 = __floats2half2_rn(ov.x, ov.y);
    __half2 p1 = __floats2half2_rn(ov.z, ov.w);
    __half2* hq = (__half2*)(h16 + (size_t)t * 4);
    hq[0] = p0;
    hq[1] = p1;
}

// ---------- graph offsets (batch is sorted) ----------
__global__ void k_goff(const int* __restrict__ batch, int* __restrict__ goff) {
    int g = blockIdx.x * 256 + threadIdx.x;
    if (g > N_GRAPHS) return;
    int lo = 0, hi = N_NODES;
    while (lo < hi) {
        int mid = (lo + hi) >> 1;
        if (batch[mid] < g) lo = mid + 1; else hi = mid;
    }
    goff[g] = lo;
}

// ---------- mean-pool: one wave per graph ----------
__global__ void __launch_bounds__(256) k_pool2(const float* __restrict__ h, const int* __restrict__ goff,
                                               float* __restrict__ gsum) {
    int wid = threadIdx.x >> 6, lane = threadIdx.x & 63;
    int g = blockIdx.x * 4 + wid;
    if (g >= N_GRAPHS) return;
    int s = goff[g], e = goff[g + 1];
    int c = lane & 31, half = lane >> 5;
    float acc = 0.f;
    for (int n = s + half; n < e; n += 2) acc += h[(size_t)n * 32 + c];
    acc += __shfl_down(acc, 32, 64);
    if (lane < 32) gsum[(size_t)g * 32 + c] = acc;
}

__global__ void k_head(const float* __restrict__ gsum, const int* __restrict__ goff,
                       const float* __restrict__ W1, const float* __restrict__ b1,
                       const float* __restrict__ W2, const float* __restrict__ b2,
                       float* __restrict__ out) {
    __shared__ float sW1[512], sb1[16], sW2[32], sb2[2];
    for (int i = threadIdx.x; i < 512; i += 256) sW1[i] = W1[i];
    if (threadIdx.x < 16) sb1[threadIdx.x] = b1[threadIdx.x];
    if (threadIdx.x < 32) sW2[threadIdx.x] = W2[threadIdx.x];
    if (threadIdx.x < 2) sb2[threadIdx.x] = b2[threadIdx.x];
    __syncthreads();
    int gI = blockIdx.x * 256 + threadIdx.x;
    if (gI >= N_GRAPHS) return;
    float cnt = (float)(goff[gI + 1] - goff[gI]);
    float inv = 1.0f / fmaxf(cnt, 1.0f);
    float gx[32];
#pragma unroll
    for (int c = 0; c < 32; c++) gx[c] = gsum[(size_t)gI * 32 + c] * inv;
    float hid[16];
#pragma unroll
    for (int j = 0; j < 16; j++) {
        float a = sb1[j];
#pragma unroll
        for (int c = 0; c < 32; c++) a += gx[c] * sW1[c * 16 + j];
        hid[j] = fmaxf(a, 0.f);
    }
#pragma unroll
    for (int o = 0; o < 2; o++) {
        float a = sb2[o];
#pragma unroll
        for (int j = 0; j < 16; j++) a += hid[j] * sW2[j * 2 + o];
        out[(size_t)gI * 2 + o] = a;
    }
}

extern "C" void kernel_launch(void* const* d_in, const int* in_sizes, int n_in,
                              void* d_out, int out_size, void* d_ws, size_t ws_size,
                              hipStream_t stream) {
    const float* x       = (const float*)d_in[0];
    const int*   ei      = (const int*)d_in[1];
    const float* eattr   = (const float*)d_in[2];
    const int*   batch   = (const int*)d_in[3];
    const float* node_w  = (const float*)d_in[4];
    const float* node_b  = (const float*)d_in[5];
    const float* edge_w  = (const float*)d_in[6];
    const float* edge_b  = (const float*)d_in[7];
    const float* conv_w1 = (const float*)d_in[8];
    const float* conv_b1 = (const float*)d_in[9];
    const float* conv_w2 = (const float*)d_in[10];
    const float* conv_b2 = (const float*)d_in[11];
    const float* bn_g    = (const float*)d_in[12];
    const float* bn_b    = (const float*)d_in[13];
    const float* lin1_w  = (const float*)d_in[14];
    const float* lin1_b  = (const float*)d_in[15];
    const float* lin2_w  = (const float*)d_in[16];
    const float* lin2_b  = (const float*)d_in[17];
    float* out = (float*)d_out;

    float4* packed = (float4*)d_ws;                        // 51.2 MB
    float4* buf1   = packed + N_EDGES;                     // 51.2 MB (CSR build only)
    float*  h      = (float*)(buf1 + N_EDGES);             // 12.8 MB
    float*  agg    = h + (size_t)N_NODES * 32;             // 12.8 MB (z in-place)
    __half* h16    = (__half*)(agg + (size_t)N_NODES * 32);// 6.4 MB
    int*    cmat   = (int*)(h16 + (size_t)N_NODES * 32);   // LALLOC ints
    int*    t1     = cmat + LALLOC;                        // 768
    int*    offs   = t1 + 768;                             // NPAD2+1
    int*    goff   = offs + NPAD2 + 1;                     // N_GRAPHS+1
    float*  stats  = (float*)(goff + N_GRAPHS + 1);        // 64
    float*  gsum   = stats + 64;                           // G*32
    float*  w1tp   = gsum + (size_t)N_GRAPHS * 32;         // 2*80*32
    float*  b1p    = w1tp + 2 * HPAD * 32;                 // 2*80
    float*  w2p    = b1p + 2 * HPAD;                       // 2*80*32

    int nb_nodes = (N_NODES + 255) / 256;
    int nb_vec   = (N_NODES * 8 + 255) / 256;

    hipMemsetAsync(cmat, 0, LALLOC * sizeof(int), stream);
    k_encode<<<nb_nodes, 256, 0, stream>>>(x, node_w, node_b, h, h16);
    k_prep<<<(2 * HPAD * 32 + 2 * HPAD + 255) / 256, 256, 0, stream>>>(
        conv_w1, conv_b1, conv_w2, w1tp, b1p, w2p);
    k_goff<<<(N_GRAPHS + 1 + 255) / 256, 256, 0, stream>>>(batch, goff);

    ksA<<<NBLKA, 256, 0, stream>>>(ei, cmat);
    ks1<<<NS1, 256, 0, stream>>>(cmat, t1);
    ks2<<<1, 256, 0, stream>>>(t1);
    ks3<<<NS1, 256, 0, stream>>>(cmat, t1);
    ksB<<<NBLKA, 256, 0, stream>>>(ei, eattr, cmat, buf1);
    ksC<<<NBKT, 1024, 0, stream>>>(cmat, buf1, packed, offs);

    for (int l = 0; l < 2; l++) {
        hipMemsetAsync(stats, 0, 64 * sizeof(float), stream);
        k_agg<<<N_NODES * 32 / 256, 256, 0, stream>>>(packed, offs, edge_w, edge_b, h16, agg);
        k_mlp<<<N_NODES * 8 / 256, 256, 0, stream>>>(h, agg, w1tp + l * HPAD * 32,
                                                     b1p + l * HPAD, w2p + l * HPAD * 32,
                                                     conv_b2 + l * 32);
        k_stats<<<256, 256, 0, stream>>>(agg, stats);
        k_bn<<<nb_vec, 256, 0, stream>>>(agg, h, h16, stats, bn_g + l * 32, bn_b + l * 32);
    }
    k_pool2<<<(N_GRAPHS + 3) / 4, 256, 0, stream>>>(h, goff, gsum);
    k_head<<<(N_GRAPHS + 255) / 256, 256, 0, stream>>>(gsum, goff, lin1_w, lin1_b, lin2_w, lin2_b, out);
}

// Round 16
// 534.506 us; speedup vs baseline: 1.1845x; 1.1489x over previous
//
#include <hip/hip_runtime.h>
#include <hip/hip_fp16.h>

#define N_NODES 100000
#define N_EDGES 3200000
#define N_GRAPHS 5000
#define BN_EPS 1e-5f
#define HPAD 80        // hidden 75 padded to 80
#define CHUNK 4096     // edges per bucket-sort block
#define NBLKA 782      // ceil(N_EDGES / CHUNK)
#define NBKT 196       // buckets of 512 nodes (dst >> 9)
#define NPAD2 (NBKT * 512)   // 100352
#define NS1 599        // ceil(NBKT*NBLKA / 256)
#define LALLOC (NS1 * 256)
#define VPT 3          // ceil(NS1 / 256) for ks2

// ---------- node encoder: h = x @ node_w + node_b (fp32 + fp16 mirror) ----------
__global__ void k_encode(const float* __restrict__ x, const float* __restrict__ W,
                         const float* __restrict__ b, float* __restrict__ h,
                         __half* __restrict__ h16) {
    __shared__ float sW[448];
    __shared__ float sb[32];
    for (int i = threadIdx.x; i < 448; i += 256) sW[i] = W[i];
    if (threadIdx.x < 32) sb[threadIdx.x] = b[threadIdx.x];
    __syncthreads();
    int n = blockIdx.x * 256 + threadIdx.x;
    if (n >= N_NODES) return;
    float xi[14];
#pragma unroll
    for (int k = 0; k < 14; k++) xi[k] = x[n * 14 + k];
    float4* hp = (float4*)(h + (size_t)n * 32);
    __half2* hq = (__half2*)(h16 + (size_t)n * 32);
#pragma unroll
    for (int q = 0; q < 8; q++) {
        float4 acc;
        float* ap = (float*)&acc;
#pragma unroll
        for (int i = 0; i < 4; i++) {
            int c = q * 4 + i;
            float a = sb[c];
#pragma unroll
            for (int k = 0; k < 14; k++) a += xi[k] * sW[k * 32 + c];
            ap[i] = a;
        }
        hp[q] = acc;
        hq[q * 2 + 0] = __floats2half2_rn(acc.x, acc.y);
        hq[q * 2 + 1] = __floats2half2_rn(acc.z, acc.w);
    }
}

// ---------- weight prep ----------
__global__ void k_prep(const float* __restrict__ W1, const float* __restrict__ b1,
                       const float* __restrict__ W2,
                       float* __restrict__ w1tp, float* __restrict__ b1p,
                       float* __restrict__ w2p) {
    int i = blockIdx.x * 256 + threadIdx.x;
    if (i < 2 * HPAD * 32) {
        int l = i / (HPAD * 32), r = i % (HPAD * 32);
        int j = r / 32, c = r % 32;
        w1tp[i] = (j < 75) ? W1[l * 2400 + c * 75 + j] : 0.f;
        w2p[i]  = (j < 75) ? W2[l * 2400 + j * 32 + c] : 0.f;
    } else if (i < 2 * HPAD * 32 + 2 * HPAD) {
        int k = i - 2 * HPAD * 32;
        int l = k / HPAD, j = k % HPAD;
        b1p[k] = (j < 75) ? b1[l * 75 + j] : 0.f;
    }
}

// ---------- bucket sort phase A: 196-bucket per-block histogram ----------
__global__ void __launch_bounds__(256) ksA(const int* __restrict__ ei, int* __restrict__ cmat) {
    __shared__ int lh[NBKT];
    if (threadIdx.x < NBKT) lh[threadIdx.x] = 0;
    __syncthreads();
    int b0 = blockIdx.x * CHUNK;
    for (int i = threadIdx.x; i < CHUNK; i += 256) {
        int e = b0 + i;
        if (e < N_EDGES) atomicAdd(&lh[ei[N_EDGES + e] >> 9], 1);
    }
    __syncthreads();
    if (threadIdx.x < NBKT) cmat[threadIdx.x * NBLKA + blockIdx.x] = lh[threadIdx.x];
}

// ---------- parallel exclusive scan of cmat ----------
__global__ void ks1(const int* __restrict__ a, int* __restrict__ bs) {
    __shared__ int s[256];
    int i = blockIdx.x * 256 + threadIdx.x;
    s[threadIdx.x] = a[i];
    __syncthreads();
    for (int o = 128; o > 0; o >>= 1) {
        if (threadIdx.x < o) s[threadIdx.x] += s[threadIdx.x + o];
        __syncthreads();
    }
    if (threadIdx.x == 0) bs[blockIdx.x] = s[0];
}

__global__ void ks2(int* __restrict__ bs) {
    __shared__ int s[256];
    int t = threadIdx.x;
    int v[VPT];
    int base = t * VPT, sum = 0;
#pragma unroll
    for (int k = 0; k < VPT; k++) {
        int idx = base + k;
        int x = (idx < NS1) ? bs[idx] : 0;
        v[k] = sum; sum += x;
    }
    s[t] = sum;
    __syncthreads();
    for (int o = 1; o < 256; o <<= 1) {
        int add = (t >= o) ? s[t - o] : 0;
        __syncthreads();
        s[t] += add;
        __syncthreads();
    }
    int excl = (t == 0) ? 0 : s[t - 1];
#pragma unroll
    for (int k = 0; k < VPT; k++) {
        int idx = base + k;
        if (idx < NS1) bs[idx] = excl + v[k];
    }
}

__global__ void ks3(int* __restrict__ a, const int* __restrict__ bs) {
    __shared__ int s[256];
    int t = threadIdx.x, i = blockIdx.x * 256 + t;
    int v = a[i];
    s[t] = v;
    __syncthreads();
    for (int o = 1; o < 256; o <<= 1) {
        int add = (t >= o) ? s[t - o] : 0;
        __syncthreads();
        s[t] += add;
        __syncthreads();
    }
    a[i] = s[t] - v + bs[blockIdx.x];
}

// ---------- phase B: scatter records into 196-bucket-grouped buf1 ----------
__global__ void __launch_bounds__(256) ksB(const int* __restrict__ ei, const float* __restrict__ ea,
                                           const int* __restrict__ cmat, float4* __restrict__ buf1) {
    __shared__ int base[NBKT];
    if (threadIdx.x < NBKT) base[threadIdx.x] = cmat[threadIdx.x * NBLKA + blockIdx.x];
    __syncthreads();
    int b0 = blockIdx.x * CHUNK;
    for (int i = threadIdx.x; i < CHUNK; i += 256) {
        int e = b0 + i;
        if (e >= N_EDGES) break;
        int src = ei[e], dst = ei[N_EDGES + e];
        float a0 = ea[(size_t)e * 3 + 0], a1 = ea[(size_t)e * 3 + 1], a2 = ea[(size_t)e * 3 + 2];
        int pos = atomicAdd(&base[dst >> 9], 1);
        buf1[pos] = make_float4(a0, a1, a2, __int_as_float(src | ((dst & 511) << 17)));
    }
}

// ---------- phase C: per-512-node-bucket exact CSR (1024-thread blocks) ----------
__global__ void __launch_bounds__(1024) ksC(const int* __restrict__ cmat, const float4* __restrict__ buf1,
                                            float4* __restrict__ packed, int* __restrict__ offs) {
    __shared__ int cnt[512];
    __shared__ int sc[512];
    __shared__ int excl[513];
    int g = blockIdx.x, t = threadIdx.x;
    int bb = cmat[g * NBLKA];
    int be = (g == NBKT - 1) ? N_EDGES : cmat[(g + 1) * NBLKA];
    if (t < 512) cnt[t] = 0;
    __syncthreads();
    for (int j = bb + t; j < be; j += 1024) {
        int bits = __float_as_int(buf1[j].w);
        atomicAdd(&cnt[bits >> 17], 1);
    }
    __syncthreads();
    if (t < 512) sc[t] = cnt[t];
    __syncthreads();
    for (int o = 1; o < 512; o <<= 1) {
        int add = 0;
        if (t < 512 && t >= o) add = sc[t - o];
        __syncthreads();
        if (t < 512) sc[t] += add;
        __syncthreads();
    }
    if (t < 512) excl[t] = sc[t] - cnt[t];
    if (t == 511) excl[512] = sc[511];
    __syncthreads();
    if (t < 512) offs[g * 512 + t] = bb + excl[t];
    if (g == NBKT - 1 && t == 0) offs[NPAD2] = N_EDGES;
    if (t < 512) cnt[t] = 0;
    __syncthreads();
    for (int j = bb + t; j < be; j += 1024) {
        float4 r = buf1[j];
        int bits = __float_as_int(r.w);
        int dl = bits >> 17, src = bits & 0x1FFFF;
        int rank = atomicAdd(&cnt[dl], 1);
        packed[bb + excl[dl] + rank] = make_float4(r.x, r.y, r.z, __int_as_float(src));
    }
}

// ---------- pull aggregation: 32 threads/node, fp16 h-gather ----------
__global__ void __launch_bounds__(256) k_agg(const float4* __restrict__ packed,
                                             const int* __restrict__ offs,
                                             const float* __restrict__ eW, const float* __restrict__ eb,
                                             const __half* __restrict__ h16, float* __restrict__ agg) {
    int t = blockIdx.x * 256 + threadIdx.x;   // N_NODES*32 exact
    int n = t >> 5, s = t & 31;
    int q = s & 7, part = s >> 3;             // quad 0..7, edge-part 0..3
    int c0 = q * 4;
    float w0[4], w1[4], w2[4], bb4[4];
#pragma unroll
    for (int i = 0; i < 4; i++) {
        w0[i] = eW[c0 + i];
        w1[i] = eW[32 + c0 + i];
        w2[i] = eW[64 + c0 + i];
        bb4[i] = eb[c0 + i];
    }
    int beg = offs[n], end = offs[n + 1];
    float acc0[4] = {0.f, 0.f, 0.f, 0.f};
    float acc1[4] = {0.f, 0.f, 0.f, 0.f};
    int j = beg + part;
    for (; j + 4 < end; j += 8) {
        float4 pa = packed[j];
        float4 pb = packed[j + 4];
        float2 ra = *(const float2*)(h16 + (size_t)__float_as_int(pa.w) * 32 + c0);
        float2 rb = *(const float2*)(h16 + (size_t)__float_as_int(pb.w) * 32 + c0);
        float2 a01 = __half22float2(*(__half2*)&ra.x);
        float2 a23 = __half22float2(*(__half2*)&ra.y);
        float2 b01 = __half22float2(*(__half2*)&rb.x);
        float2 b23 = __half22float2(*(__half2*)&rb.y);
        float ha4[4] = {a01.x, a01.y, a23.x, a23.y};
        float hb4[4] = {b01.x, b01.y, b23.x, b23.y};
#pragma unroll
        for (int i = 0; i < 4; i++) {
            acc0[i] += fmaxf(ha4[i] + pa.x * w0[i] + pa.y * w1[i] + pa.z * w2[i] + bb4[i], 0.f);
            acc1[i] += fmaxf(hb4[i] + pb.x * w0[i] + pb.y * w1[i] + pb.z * w2[i] + bb4[i], 0.f);
        }
    }
    if (j < end) {
        float4 p = packed[j];
        float2 r = *(const float2*)(h16 + (size_t)__float_as_int(p.w) * 32 + c0);
        float2 a01 = __half22float2(*(__half2*)&r.x);
        float2 a23 = __half22float2(*(__half2*)&r.y);
        float hp4[4] = {a01.x, a01.y, a23.x, a23.y};
#pragma unroll
        for (int i = 0; i < 4; i++)
            acc0[i] += fmaxf(hp4[i] + p.x * w0[i] + p.y * w1[i] + p.z * w2[i] + bb4[i], 0.f);
    }
    float acc[4];
#pragma unroll
    for (int i = 0; i < 4; i++) {
        acc[i] = acc0[i] + acc1[i];
        acc[i] += __shfl_xor(acc[i], 8, 64);
        acc[i] += __shfl_xor(acc[i], 16, 64);
    }
    if (part == 0)
        *(float4*)(agg + (size_t)n * 32 + c0) = make_float4(acc[0], acc[1], acc[2], acc[3]);
}

// ---------- fused MLP: z = relu((h+agg)@W1+b1)@W2+b2, written over agg ----------
// Weights staged in LDS once per block: weight reads become 8-distinct-address
// ds_read_b128 broadcasts (exactly covering the 32 banks -> conflict-free),
// immune to L1 eviction by the streaming h/agg loads.
__global__ void __launch_bounds__(256, 4) k_mlp(const float* __restrict__ h, float* __restrict__ agg,
                                                const float* __restrict__ W1, const float* __restrict__ B1,
                                                const float* __restrict__ W2, const float* __restrict__ b2) {
    __shared__ float sW1[2560];        // [j(80)][c(32)]
    __shared__ float sW2[2560];        // [j(80)][c(32)]
    __shared__ float sB1[80];
    __shared__ float sb2[32];
    __shared__ float hidL[32 * 84];    // 4 waves * 8 nodes; stride 84
    for (int i = threadIdx.x; i < 2560; i += 256) { sW1[i] = W1[i]; sW2[i] = W2[i]; }
    if (threadIdx.x < 80) sB1[threadIdx.x] = B1[threadIdx.x];
    if (threadIdx.x < 32) sb2[threadIdx.x] = b2[threadIdx.x];
    __syncthreads();
    unsigned t = blockIdx.x * 256 + threadIdx.x;   // N_NODES*8 exact
    unsigned lane = threadIdx.x & 63;
    unsigned wv = threadIdx.x >> 6;
    unsigned oct = lane >> 3;
    unsigned nd = lane & 7;
    unsigned n = (t >> 6) * 8 + nd;
    const float4* hp = (const float4*)(h + (size_t)n * 32);
    const float4* ap = (const float4*)(agg + (size_t)n * 32);
    float zc[32];
#pragma unroll
    for (int q = 0; q < 8; q++) {
        float4 hv = hp[q], av = ap[q];
        zc[q * 4 + 0] = hv.x + av.x;
        zc[q * 4 + 1] = hv.y + av.y;
        zc[q * 4 + 2] = hv.z + av.z;
        zc[q * 4 + 3] = hv.w + av.w;
    }
    float hid[10];
#pragma unroll
    for (int i = 0; i < 10; i++) {
        int j = (int)oct * 10 + i;
        const float4* wp = (const float4*)(sW1 + j * 32);
        float a0 = 0.f, a1 = 0.f, a2 = 0.f, a3 = 0.f;
#pragma unroll
        for (int q = 0; q < 8; q++) {
            float4 wv4 = wp[q];
            a0 += zc[q * 4 + 0] * wv4.x;
            a1 += zc[q * 4 + 1] * wv4.y;
            a2 += zc[q * 4 + 2] * wv4.z;
            a3 += zc[q * 4 + 3] * wv4.w;
        }
        hid[i] = fmaxf(sB1[j] + ((a0 + a1) + (a2 + a3)), 0.f);
    }
    float* hrow = &hidL[(wv * 8 + nd) * 84];
#pragma unroll
    for (int i = 0; i < 10; i++) hrow[oct * 10 + i] = hid[i];
    float4 zo = *(const float4*)(sb2 + oct * 4);
    const float4* hv4 = (const float4*)hrow;
#pragma unroll
    for (int k = 0; k < 20; k++) {
        float4 hv = hv4[k];
        const float* wr = sW2 + (k * 4) * 32 + oct * 4;
        float4 wa = *(const float4*)(wr);
        float4 wb = *(const float4*)(wr + 32);
        float4 wc = *(const float4*)(wr + 64);
        float4 wd = *(const float4*)(wr + 96);
        zo.x += hv.x * wa.x + hv.y * wb.x + hv.z * wc.x + hv.w * wd.x;
        zo.y += hv.x * wa.y + hv.y * wb.y + hv.z * wc.y + hv.w * wd.y;
        zo.z += hv.x * wa.z + hv.y * wb.z + hv.z * wc.z + hv.w * wd.z;
        zo.w += hv.x * wa.w + hv.y * wb.w + hv.z * wc.w + hv.w * wd.w;
    }
    *(float4*)(agg + (size_t)n * 32 + oct * 4) = zo;
}

// ---------- BN stats ----------
__global__ void __launch_bounds__(256) k_stats(const float* __restrict__ z, float* __restrict__ stats) {
    __shared__ float ls[4 * 64];
    int tid = threadIdx.x;
    int c = tid & 31;
    float s = 0.f, s2 = 0.f;
    for (int e = blockIdx.x * 256 + tid; e < N_NODES * 32; e += 256 * 256) {
        float v = z[e];
        s += v; s2 += v * v;
    }
    s += __shfl_down(s, 32, 64);
    s2 += __shfl_down(s2, 32, 64);
    int wave = tid >> 6, lane = tid & 63;
    if (lane < 32) { ls[wave * 64 + c] = s; ls[wave * 64 + 32 + c] = s2; }
    __syncthreads();
    if (tid < 64) {
        float a = ls[tid] + ls[64 + tid] + ls[128 + tid] + ls[192 + tid];
        atomicAdd(&stats[tid], a);
    }
}

// ---------- BN apply + relu (fp32 h + fp16 mirror) ----------
__global__ void k_bn(const float* __restrict__ z, float* __restrict__ h,
                     __half* __restrict__ h16,
                     const float* __restrict__ stats, const float* __restrict__ g,
                     const float* __restrict__ b) {
    int t = blockIdx.x * 256 + threadIdx.x;
    if (t >= N_NODES * 8) return;
    int q = t & 7;
    float4 zv = ((const float4*)z)[t];
    float* zp = (float*)&zv;
    float4 ov;
    float* op = (float*)&ov;
    const float invN = 1.0f / (float)N_NODES;
#pragma unroll
    for (int i = 0; i < 4; i++) {
        int c = q * 4 + i;
        float mu = stats[c] * invN;
        float var = stats[32 + c] * invN - mu * mu;
        float sc = g[c] / sqrtf(var + BN_EPS);
        op[i] = fmaxf((zp[i] - mu) * sc + b[c], 0.f);
    }
    ((float4*)h)[t] = ov;
    __half2 p0 = __floats2half2_rn(ov.x, ov.y);
    __half2 p1 = __floats2half2_rn(ov.z, ov.w);
    __half2* hq = (__half2*)(h16 + (size_t)t * 4);
    hq[0] = p0;
    hq[1] = p1;
}

// ---------- graph offsets (batch is sorted) ----------
__global__ void k_goff(const int* __restrict__ batch, int* __restrict__ goff) {
    int g = blockIdx.x * 256 + threadIdx.x;
    if (g > N_GRAPHS) return;
    int lo = 0, hi = N_NODES;
    while (lo < hi) {
        int mid = (lo + hi) >> 1;
        if (batch[mid] < g) lo = mid + 1; else hi = mid;
    }
    goff[g] = lo;
}

// ---------- mean-pool: one wave per graph ----------
__global__ void __launch_bounds__(256) k_pool2(const float* __restrict__ h, const int* __restrict__ goff,
                                               float* __restrict__ gsum) {
    int wid = threadIdx.x >> 6, lane = threadIdx.x & 63;
    int g = blockIdx.x * 4 + wid;
    if (g >= N_GRAPHS) return;
    int s = goff[g], e = goff[g + 1];
    int c = lane & 31, half = lane >> 5;
    float acc = 0.f;
    for (int n = s + half; n < e; n += 2) acc += h[(size_t)n * 32 + c];
    acc += __shfl_down(acc, 32, 64);
    if (lane < 32) gsum[(size_t)g * 32 + c] = acc;
}

__global__ void k_head(const float* __restrict__ gsum, const int* __restrict__ goff,
                       const float* __restrict__ W1, const float* __restrict__ b1,
                       const float* __restrict__ W2, const float* __restrict__ b2,
                       float* __restrict__ out) {
    __shared__ float sW1[512], sb1[16], sW2[32], sb2[2];
    for (int i = threadIdx.x; i < 512; i += 256) sW1[i] = W1[i];
    if (threadIdx.x < 16) sb1[threadIdx.x] = b1[threadIdx.x];
    if (threadIdx.x < 32) sW2[threadIdx.x] = W2[threadIdx.x];
    if (threadIdx.x < 2) sb2[threadIdx.x] = b2[threadIdx.x];
    __syncthreads();
    int gI = blockIdx.x * 256 + threadIdx.x;
    if (gI >= N_GRAPHS) return;
    float cnt = (float)(goff[gI + 1] - goff[gI]);
    float inv = 1.0f / fmaxf(cnt, 1.0f);
    float gx[32];
#pragma unroll
    for (int c = 0; c < 32; c++) gx[c] = gsum[(size_t)gI * 32 + c] * inv;
    float hid[16];
#pragma unroll
    for (int j = 0; j < 16; j++) {
        float a = sb1[j];
#pragma unroll
        for (int c = 0; c < 32; c++) a += gx[c] * sW1[c * 16 + j];
        hid[j] = fmaxf(a, 0.f);
    }
#pragma unroll
    for (int o = 0; o < 2; o++) {
        float a = sb2[o];
#pragma unroll
        for (int j = 0; j < 16; j++) a += hid[j] * sW2[j * 2 + o];
        out[(size_t)gI * 2 + o] = a;
    }
}

extern "C" void kernel_launch(void* const* d_in, const int* in_sizes, int n_in,
                              void* d_out, int out_size, void* d_ws, size_t ws_size,
                              hipStream_t stream) {
    const float* x       = (const float*)d_in[0];
    const int*   ei      = (const int*)d_in[1];
    const float* eattr   = (const float*)d_in[2];
    const int*   batch   = (const int*)d_in[3];
    const float* node_w  = (const float*)d_in[4];
    const float* node_b  = (const float*)d_in[5];
    const float* edge_w  = (const float*)d_in[6];
    const float* edge_b  = (const float*)d_in[7];
    const float* conv_w1 = (const float*)d_in[8];
    const float* conv_b1 = (const float*)d_in[9];
    const float* conv_w2 = (const float*)d_in[10];
    const float* conv_b2 = (const float*)d_in[11];
    const float* bn_g    = (const float*)d_in[12];
    const float* bn_b    = (const float*)d_in[13];
    const float* lin1_w  = (const float*)d_in[14];
    const float* lin1_b  = (const float*)d_in[15];
    const float* lin2_w  = (const float*)d_in[16];
    const float* lin2_b  = (const float*)d_in[17];
    float* out = (float*)d_out;

    float4* packed = (float4*)d_ws;                        // 51.2 MB
    float4* buf1   = packed + N_EDGES;                     // 51.2 MB (CSR build only)
    float*  h      = (float*)(buf1 + N_EDGES);             // 12.8 MB
    float*  agg    = h + (size_t)N_NODES * 32;             // 12.8 MB (z in-place)
    __half* h16    = (__half*)(agg + (size_t)N_NODES * 32);// 6.4 MB
    int*    cmat   = (int*)(h16 + (size_t)N_NODES * 32);   // LALLOC ints
    int*    t1     = cmat + LALLOC;                        // 768
    int*    offs   = t1 + 768;                             // NPAD2+1
    int*    goff   = offs + NPAD2 + 1;                     // N_GRAPHS+1
    float*  stats  = (float*)(goff + N_GRAPHS + 1);        // 64
    float*  gsum   = stats + 64;                           // G*32
    float*  w1tp   = gsum + (size_t)N_GRAPHS * 32;         // 2*80*32
    float*  b1p    = w1tp + 2 * HPAD * 32;                 // 2*80
    float*  w2p    = b1p + 2 * HPAD;                       // 2*80*32

    int nb_nodes = (N_NODES + 255) / 256;
    int nb_vec   = (N_NODES * 8 + 255) / 256;

    hipMemsetAsync(cmat, 0, LALLOC * sizeof(int), stream);
    k_encode<<<nb_nodes, 256, 0, stream>>>(x, node_w, node_b, h, h16);
    k_prep<<<(2 * HPAD * 32 + 2 * HPAD + 255) / 256, 256, 0, stream>>>(
        conv_w1, conv_b1, conv_w2, w1tp, b1p, w2p);
    k_goff<<<(N_GRAPHS + 1 + 255) / 256, 256, 0, stream>>>(batch, goff);

    ksA<<<NBLKA, 256, 0, stream>>>(ei, cmat);
    ks1<<<NS1, 256, 0, stream>>>(cmat, t1);
    ks2<<<1, 256, 0, stream>>>(t1);
    ks3<<<NS1, 256, 0, stream>>>(cmat, t1);
    ksB<<<NBLKA, 256, 0, stream>>>(ei, eattr, cmat, buf1);
    ksC<<<NBKT, 1024, 0, stream>>>(cmat, buf1, packed, offs);

    for (int l = 0; l < 2; l++) {
        hipMemsetAsync(stats, 0, 64 * sizeof(float), stream);
        k_agg<<<N_NODES * 32 / 256, 256, 0, stream>>>(packed, offs, edge_w, edge_b, h16, agg);
        k_mlp<<<N_NODES * 8 / 256, 256, 0, stream>>>(h, agg, w1tp + l * HPAD * 32,
                                                     b1p + l * HPAD, w2p + l * HPAD * 32,
                                                     conv_b2 + l * 32);
        k_stats<<<256, 256, 0, stream>>>(agg, stats);
        k_bn<<<nb_vec, 256, 0, stream>>>(agg, h, h16, stats, bn_g + l * 32, bn_b + l * 32);
    }
    k_pool2<<<(N_GRAPHS + 3) / 4, 256, 0, stream>>>(h, goff, gsum);
    k_head<<<(N_GRAPHS + 255) / 256, 256, 0, stream>>>(gsum, goff, lin1_w, lin1_b, lin2_w, lin2_b, out);
}

// Round 17
// 493.847 us; speedup vs baseline: 1.2820x; 1.0823x over previous
//
#include <hip/hip_runtime.h>
#include <hip/hip_fp16.h>

#define N_NODES 100000
#define N_EDGES 3200000
#define N_GRAPHS 5000
#define BN_EPS 1e-5f
#define HPAD 80        // hidden 75 padded to 80
#define CHUNK 2048     // edges per bucket-sort block
#define NBLKA 1563     // ceil(N_EDGES / CHUNK)
#define NBKT 196       // buckets of 512 nodes (dst >> 9)
#define NPAD2 (NBKT * 512)   // 100352
#define NS1 1197       // ceil(NBKT*NBLKA / 256) = ceil(306348/256)
#define LALLOC (NS1 * 256)
#define VPT 5          // ceil(NS1 / 256) for ks2

// ---------- node encoder: h = x @ node_w + node_b (fp32 + fp16 mirror) ----------
__global__ void k_encode(const float* __restrict__ x, const float* __restrict__ W,
                         const float* __restrict__ b, float* __restrict__ h,
                         __half* __restrict__ h16) {
    __shared__ float sW[448];
    __shared__ float sb[32];
    for (int i = threadIdx.x; i < 448; i += 256) sW[i] = W[i];
    if (threadIdx.x < 32) sb[threadIdx.x] = b[threadIdx.x];
    __syncthreads();
    int n = blockIdx.x * 256 + threadIdx.x;
    if (n >= N_NODES) return;
    float xi[14];
#pragma unroll
    for (int k = 0; k < 14; k++) xi[k] = x[n * 14 + k];
    float4* hp = (float4*)(h + (size_t)n * 32);
    __half2* hq = (__half2*)(h16 + (size_t)n * 32);
#pragma unroll
    for (int q = 0; q < 8; q++) {
        float4 acc;
        float* ap = (float*)&acc;
#pragma unroll
        for (int i = 0; i < 4; i++) {
            int c = q * 4 + i;
            float a = sb[c];
#pragma unroll
            for (int k = 0; k < 14; k++) a += xi[k] * sW[k * 32 + c];
            ap[i] = a;
        }
        hp[q] = acc;
        hq[q * 2 + 0] = __floats2half2_rn(acc.x, acc.y);
        hq[q * 2 + 1] = __floats2half2_rn(acc.z, acc.w);
    }
}

// ---------- weight prep ----------
__global__ void k_prep(const float* __restrict__ W1, const float* __restrict__ b1,
                       const float* __restrict__ W2,
                       float* __restrict__ w1tp, float* __restrict__ b1p,
                       float* __restrict__ w2p) {
    int i = blockIdx.x * 256 + threadIdx.x;
    if (i < 2 * HPAD * 32) {
        int l = i / (HPAD * 32), r = i % (HPAD * 32);
        int j = r / 32, c = r % 32;
        w1tp[i] = (j < 75) ? W1[l * 2400 + c * 75 + j] : 0.f;
        w2p[i]  = (j < 75) ? W2[l * 2400 + j * 32 + c] : 0.f;
    } else if (i < 2 * HPAD * 32 + 2 * HPAD) {
        int k = i - 2 * HPAD * 32;
        int l = k / HPAD, j = k % HPAD;
        b1p[k] = (j < 75) ? b1[l * 75 + j] : 0.f;
    }
}

// ---------- bucket sort phase A: 196-bucket per-block histogram ----------
__global__ void __launch_bounds__(256) ksA(const int* __restrict__ ei, int* __restrict__ cmat) {
    __shared__ int lh[NBKT];
    if (threadIdx.x < NBKT) lh[threadIdx.x] = 0;
    __syncthreads();
    int b0 = blockIdx.x * CHUNK;
    for (int i = threadIdx.x; i < CHUNK; i += 256) {
        int e = b0 + i;
        if (e < N_EDGES) atomicAdd(&lh[ei[N_EDGES + e] >> 9], 1);
    }
    __syncthreads();
    if (threadIdx.x < NBKT) cmat[threadIdx.x * NBLKA + blockIdx.x] = lh[threadIdx.x];
}

// ---------- parallel exclusive scan of cmat ----------
__global__ void ks1(const int* __restrict__ a, int* __restrict__ bs) {
    __shared__ int s[256];
    int i = blockIdx.x * 256 + threadIdx.x;
    s[threadIdx.x] = a[i];
    __syncthreads();
    for (int o = 128; o > 0; o >>= 1) {
        if (threadIdx.x < o) s[threadIdx.x] += s[threadIdx.x + o];
        __syncthreads();
    }
    if (threadIdx.x == 0) bs[blockIdx.x] = s[0];
}

__global__ void ks2(int* __restrict__ bs) {
    __shared__ int s[256];
    int t = threadIdx.x;
    int v[VPT];
    int base = t * VPT, sum = 0;
#pragma unroll
    for (int k = 0; k < VPT; k++) {
        int idx = base + k;
        int x = (idx < NS1) ? bs[idx] : 0;
        v[k] = sum; sum += x;
    }
    s[t] = sum;
    __syncthreads();
    for (int o = 1; o < 256; o <<= 1) {
        int add = (t >= o) ? s[t - o] : 0;
        __syncthreads();
        s[t] += add;
        __syncthreads();
    }
    int excl = (t == 0) ? 0 : s[t - 1];
#pragma unroll
    for (int k = 0; k < VPT; k++) {
        int idx = base + k;
        if (idx < NS1) bs[idx] = excl + v[k];
    }
}

__global__ void ks3(int* __restrict__ a, const int* __restrict__ bs) {
    __shared__ int s[256];
    int t = threadIdx.x, i = blockIdx.x * 256 + t;
    int v = a[i];
    s[t] = v;
    __syncthreads();
    for (int o = 1; o < 256; o <<= 1) {
        int add = (t >= o) ? s[t - o] : 0;
        __syncthreads();
        s[t] += add;
        __syncthreads();
    }
    a[i] = s[t] - v + bs[blockIdx.x];
}

// ---------- phase B: per-block counting sort in LDS, then coalesced drain ----------
__global__ void __launch_bounds__(256) ksB(const int* __restrict__ ei, const float* __restrict__ ea,
                                           const int* __restrict__ cmat, float4* __restrict__ buf1) {
    __shared__ float4 rec[CHUNK];              // 32 KB sorted records
    __shared__ unsigned short sbkt[CHUNK];     // 4 KB bucket tag per rank
    __shared__ int lh[NBKT];                   // histogram -> cursor
    __shared__ int lex[NBKT];                  // local exclusive offsets
    __shared__ int gb[NBKT];                   // global base for (bucket, this block)
    __shared__ int sc[256];                    // scan temp
    int t = threadIdx.x;
    int b0 = blockIdx.x * CHUNK;
    int nval = min(CHUNK, N_EDGES - b0);
    if (t < NBKT) lh[t] = 0;
    __syncthreads();
    // pass 1: local histogram
    for (int i = t; i < nval; i += 256)
        atomicAdd(&lh[ei[N_EDGES + b0 + i] >> 9], 1);
    __syncthreads();
    // scan 196 counters (Hillis-Steele over 256 padded)
    sc[t] = (t < NBKT) ? lh[t] : 0;
    __syncthreads();
    for (int o = 1; o < 256; o <<= 1) {
        int add = (t >= o) ? sc[t - o] : 0;
        __syncthreads();
        sc[t] += add;
        __syncthreads();
    }
    if (t < NBKT) {
        lex[t] = sc[t] - lh[t];
        gb[t] = cmat[t * NBLKA + blockIdx.x];
        lh[t] = sc[t] - lh[t];   // cursor = exclusive offset
    }
    __syncthreads();
    // pass 2: rank-scatter records into LDS
    for (int i = t; i < nval; i += 256) {
        int e = b0 + i;
        int src = ei[e], dst = ei[N_EDGES + e];
        float a0 = ea[(size_t)e * 3 + 0], a1 = ea[(size_t)e * 3 + 1], a2 = ea[(size_t)e * 3 + 2];
        int bkt = dst >> 9;
        int r = atomicAdd(&lh[bkt], 1);
        rec[r] = make_float4(a0, a1, a2, __int_as_float(src | ((dst & 511) << 17)));
        sbkt[r] = (unsigned short)bkt;
    }
    __syncthreads();
    // pass 3: coalesced drain (consecutive ranks -> consecutive global slots)
    for (int p = t; p < nval; p += 256) {
        int bkt = sbkt[p];
        buf1[gb[bkt] + (p - lex[bkt])] = rec[p];
    }
}

// ---------- phase C: per-512-node-bucket exact CSR (1024-thread blocks) ----------
__global__ void __launch_bounds__(1024) ksC(const int* __restrict__ cmat, const float4* __restrict__ buf1,
                                            float4* __restrict__ packed, int* __restrict__ offs) {
    __shared__ int cnt[512];
    __shared__ int sc[512];
    __shared__ int excl[513];
    int g = blockIdx.x, t = threadIdx.x;
    int bb = cmat[g * NBLKA];
    int be = (g == NBKT - 1) ? N_EDGES : cmat[(g + 1) * NBLKA];
    if (t < 512) cnt[t] = 0;
    __syncthreads();
    for (int j = bb + t; j < be; j += 1024) {
        int bits = __float_as_int(buf1[j].w);
        atomicAdd(&cnt[bits >> 17], 1);
    }
    __syncthreads();
    if (t < 512) sc[t] = cnt[t];
    __syncthreads();
    for (int o = 1; o < 512; o <<= 1) {
        int add = 0;
        if (t < 512 && t >= o) add = sc[t - o];
        __syncthreads();
        if (t < 512) sc[t] += add;
        __syncthreads();
    }
    if (t < 512) excl[t] = sc[t] - cnt[t];
    if (t == 511) excl[512] = sc[511];
    __syncthreads();
    if (t < 512) offs[g * 512 + t] = bb + excl[t];
    if (g == NBKT - 1 && t == 0) offs[NPAD2] = N_EDGES;
    if (t < 512) cnt[t] = 0;
    __syncthreads();
    for (int j = bb + t; j < be; j += 1024) {
        float4 r = buf1[j];
        int bits = __float_as_int(r.w);
        int dl = bits >> 17, src = bits & 0x1FFFF;
        int rank = atomicAdd(&cnt[dl], 1);
        packed[bb + excl[dl] + rank] = make_float4(r.x, r.y, r.z, __int_as_float(src));
    }
}

// ---------- pull aggregation: 32 threads/node, fp16 h-gather ----------
__global__ void __launch_bounds__(256) k_agg(const float4* __restrict__ packed,
                                             const int* __restrict__ offs,
                                             const float* __restrict__ eW, const float* __restrict__ eb,
                                             const __half* __restrict__ h16, float* __restrict__ agg) {
    int t = blockIdx.x * 256 + threadIdx.x;   // N_NODES*32 exact
    int n = t >> 5, s = t & 31;
    int q = s & 7, part = s >> 3;             // quad 0..7, edge-part 0..3
    int c0 = q * 4;
    float w0[4], w1[4], w2[4], bb4[4];
#pragma unroll
    for (int i = 0; i < 4; i++) {
        w0[i] = eW[c0 + i];
        w1[i] = eW[32 + c0 + i];
        w2[i] = eW[64 + c0 + i];
        bb4[i] = eb[c0 + i];
    }
    int beg = offs[n], end = offs[n + 1];
    float acc0[4] = {0.f, 0.f, 0.f, 0.f};
    float acc1[4] = {0.f, 0.f, 0.f, 0.f};
    int j = beg + part;
    for (; j + 4 < end; j += 8) {
        float4 pa = packed[j];
        float4 pb = packed[j + 4];
        float2 ra = *(const float2*)(h16 + (size_t)__float_as_int(pa.w) * 32 + c0);
        float2 rb = *(const float2*)(h16 + (size_t)__float_as_int(pb.w) * 32 + c0);
        float2 a01 = __half22float2(*(__half2*)&ra.x);
        float2 a23 = __half22float2(*(__half2*)&ra.y);
        float2 b01 = __half22float2(*(__half2*)&rb.x);
        float2 b23 = __half22float2(*(__half2*)&rb.y);
        float ha4[4] = {a01.x, a01.y, a23.x, a23.y};
        float hb4[4] = {b01.x, b01.y, b23.x, b23.y};
#pragma unroll
        for (int i = 0; i < 4; i++) {
            acc0[i] += fmaxf(ha4[i] + pa.x * w0[i] + pa.y * w1[i] + pa.z * w2[i] + bb4[i], 0.f);
            acc1[i] += fmaxf(hb4[i] + pb.x * w0[i] + pb.y * w1[i] + pb.z * w2[i] + bb4[i], 0.f);
        }
    }
    if (j < end) {
        float4 p = packed[j];
        float2 r = *(const float2*)(h16 + (size_t)__float_as_int(p.w) * 32 + c0);
        float2 a01 = __half22float2(*(__half2*)&r.x);
        float2 a23 = __half22float2(*(__half2*)&r.y);
        float hp4[4] = {a01.x, a01.y, a23.x, a23.y};
#pragma unroll
        for (int i = 0; i < 4; i++)
            acc0[i] += fmaxf(hp4[i] + p.x * w0[i] + p.y * w1[i] + p.z * w2[i] + bb4[i], 0.f);
    }
    float acc[4];
#pragma unroll
    for (int i = 0; i < 4; i++) {
        acc[i] = acc0[i] + acc1[i];
        acc[i] += __shfl_xor(acc[i], 8, 64);
        acc[i] += __shfl_xor(acc[i], 16, 64);
    }
    if (part == 0)
        *(float4*)(agg + (size_t)n * 32 + c0) = make_float4(acc[0], acc[1], acc[2], acc[3]);
}

// ---------- fused MLP: z = relu((h+agg)@W1+b1)@W2+b2, written over agg ----------
// Weights staged in LDS once per block (conflict-free ds_read_b128 broadcasts).
__global__ void __launch_bounds__(256, 4) k_mlp(const float* __restrict__ h, float* __restrict__ agg,
                                                const float* __restrict__ W1, const float* __restrict__ B1,
                                                const float* __restrict__ W2, const float* __restrict__ b2) {
    __shared__ float sW1[2560];        // [j(80)][c(32)]
    __shared__ float sW2[2560];        // [j(80)][c(32)]
    __shared__ float sB1[80];
    __shared__ float sb2[32];
    __shared__ float hidL[32 * 84];    // 4 waves * 8 nodes; stride 84
    for (int i = threadIdx.x; i < 2560; i += 256) { sW1[i] = W1[i]; sW2[i] = W2[i]; }
    if (threadIdx.x < 80) sB1[threadIdx.x] = B1[threadIdx.x];
    if (threadIdx.x < 32) sb2[threadIdx.x] = b2[threadIdx.x];
    __syncthreads();
    unsigned t = blockIdx.x * 256 + threadIdx.x;   // N_NODES*8 exact
    unsigned lane = threadIdx.x & 63;
    unsigned wv = threadIdx.x >> 6;
    unsigned oct = lane >> 3;
    unsigned nd = lane & 7;
    unsigned n = (t >> 6) * 8 + nd;
    const float4* hp = (const float4*)(h + (size_t)n * 32);
    const float4* ap = (const float4*)(agg + (size_t)n * 32);
    float zc[32];
#pragma unroll
    for (int q = 0; q < 8; q++) {
        float4 hv = hp[q], av = ap[q];
        zc[q * 4 + 0] = hv.x + av.x;
        zc[q * 4 + 1] = hv.y + av.y;
        zc[q * 4 + 2] = hv.z + av.z;
        zc[q * 4 + 3] = hv.w + av.w;
    }
    float hid[10];
#pragma unroll
    for (int i = 0; i < 10; i++) {
        int j = (int)oct * 10 + i;
        const float4* wp = (const float4*)(sW1 + j * 32);
        float a0 = 0.f, a1 = 0.f, a2 = 0.f, a3 = 0.f;
#pragma unroll
        for (int q = 0; q < 8; q++) {
            float4 wv4 = wp[q];
            a0 += zc[q * 4 + 0] * wv4.x;
            a1 += zc[q * 4 + 1] * wv4.y;
            a2 += zc[q * 4 + 2] * wv4.z;
            a3 += zc[q * 4 + 3] * wv4.w;
        }
        hid[i] = fmaxf(sB1[j] + ((a0 + a1) + (a2 + a3)), 0.f);
    }
    float* hrow = &hidL[(wv * 8 + nd) * 84];
#pragma unroll
    for (int i = 0; i < 10; i++) hrow[oct * 10 + i] = hid[i];
    float4 zo = *(const float4*)(sb2 + oct * 4);
    const float4* hv4 = (const float4*)hrow;
#pragma unroll
    for (int k = 0; k < 20; k++) {
        float4 hv = hv4[k];
        const float* wr = sW2 + (k * 4) * 32 + oct * 4;
        float4 wa = *(const float4*)(wr);
        float4 wb = *(const float4*)(wr + 32);
        float4 wc = *(const float4*)(wr + 64);
        float4 wd = *(const float4*)(wr + 96);
        zo.x += hv.x * wa.x + hv.y * wb.x + hv.z * wc.x + hv.w * wd.x;
        zo.y += hv.x * wa.y + hv.y * wb.y + hv.z * wc.y + hv.w * wd.y;
        zo.z += hv.x * wa.z + hv.y * wb.z + hv.z * wc.z + hv.w * wd.z;
        zo.w += hv.x * wa.w + hv.y * wb.w + hv.z * wc.w + hv.w * wd.w;
    }
    *(float4*)(agg + (size_t)n * 32 + oct * 4) = zo;
}

// ---------- BN stats ----------
__global__ void __launch_bounds__(256) k_stats(const float* __restrict__ z, float* __restrict__ stats) {
    __shared__ float ls[4 * 64];
    int tid = threadIdx.x;
    int c = tid & 31;
    float s = 0.f, s2 = 0.f;
    for (int e = blockIdx.x * 256 + tid; e < N_NODES * 32; e += 256 * 256) {
        float v = z[e];
        s += v; s2 += v * v;
    }
    s += __shfl_down(s, 32, 64);
    s2 += __shfl_down(s2, 32, 64);
    int wave = tid >> 6, lane = tid & 63;
    if (lane < 32) { ls[wave * 64 + c] = s; ls[wave * 64 + 32 + c] = s2; }
    __syncthreads();
    if (tid < 64) {
        float a = ls[tid] + ls[64 + tid] + ls[128 + tid] + ls[192 + tid];
        atomicAdd(&stats[tid], a);
    }
}

// ---------- BN apply + relu (fp32 h + fp16 mirror) ----------
__global__ void k_bn(const float* __restrict__ z, float* __restrict__ h,
                     __half* __restrict__ h16,
                     const float* __restrict__ stats, const float* __restrict__ g,
                     const float* __restrict__ b) {
    int t = blockIdx.x * 256 + threadIdx.x;
    if (t >= N_NODES * 8) return;
    int q = t & 7;
    float4 zv = ((const float4*)z)[t];
    float* zp = (float*)&zv;
    float4 ov;
    float* op = (float*)&ov;
    const float invN = 1.0f / (float)N_NODES;
#pragma unroll
    for (int i = 0; i < 4; i++) {
        int c = q * 4 + i;
        float mu = stats[c] * invN;
        float var = stats[32 + c] * invN - mu * mu;
        float sc = g[c] / sqrtf(var + BN_EPS);
        op[i] = fmaxf((zp[i] - mu) * sc + b[c], 0.f);
    }
    ((float4*)h)[t] = ov;
    __half2 p0 = __floats2half2_rn(ov.x, ov.y);
    __half2 p1 = __floats2half2_rn(ov.z, ov.w);
    __half2* hq = (__half2*)(h16 + (size_t)t * 4);
    hq[0] = p0;
    hq[1] = p1;
}

// ---------- graph offsets (batch is sorted) ----------
__global__ void k_goff(const int* __restrict__ batch, int* __restrict__ goff) {
    int g = blockIdx.x * 256 + threadIdx.x;
    if (g > N_GRAPHS) return;
    int lo = 0, hi = N_NODES;
    while (lo < hi) {
        int mid = (lo + hi) >> 1;
        if (batch[mid] < g) lo = mid + 1; else hi = mid;
    }
    goff[g] = lo;
}

// ---------- mean-pool: one wave per graph ----------
__global__ void __launch_bounds__(256) k_pool2(const float* __restrict__ h, const int* __restrict__ goff,
                                               float* __restrict__ gsum) {
    int wid = threadIdx.x >> 6, lane = threadIdx.x & 63;
    int g = blockIdx.x * 4 + wid;
    if (g >= N_GRAPHS) return;
    int s = goff[g], e = goff[g + 1];
    int c = lane & 31, half = lane >> 5;
    float acc = 0.f;
    for (int n = s + half; n < e; n += 2) acc += h[(size_t)n * 32 + c];
    acc += __shfl_down(acc, 32, 64);
    if (lane < 32) gsum[(size_t)g * 32 + c] = acc;
}

__global__ void k_head(const float* __restrict__ gsum, const int* __restrict__ goff,
                       const float* __restrict__ W1, const float* __restrict__ b1,
                       const float* __restrict__ W2, const float* __restrict__ b2,
                       float* __restrict__ out) {
    __shared__ float sW1[512], sb1[16], sW2[32], sb2[2];
    for (int i = threadIdx.x; i < 512; i += 256) sW1[i] = W1[i];
    if (threadIdx.x < 16) sb1[threadIdx.x] = b1[threadIdx.x];
    if (threadIdx.x < 32) sW2[threadIdx.x] = W2[threadIdx.x];
    if (threadIdx.x < 2) sb2[threadIdx.x] = b2[threadIdx.x];
    __syncthreads();
    int gI = blockIdx.x * 256 + threadIdx.x;
    if (gI >= N_GRAPHS) return;
    float cnt = (float)(goff[gI + 1] - goff[gI]);
    float inv = 1.0f / fmaxf(cnt, 1.0f);
    float gx[32];
#pragma unroll
    for (int c = 0; c < 32; c++) gx[c] = gsum[(size_t)gI * 32 + c] * inv;
    float hid[16];
#pragma unroll
    for (int j = 0; j < 16; j++) {
        float a = sb1[j];
#pragma unroll
        for (int c = 0; c < 32; c++) a += gx[c] * sW1[c * 16 + j];
        hid[j] = fmaxf(a, 0.f);
    }
#pragma unroll
    for (int o = 0; o < 2; o++) {
        float a = sb2[o];
#pragma unroll
        for (int j = 0; j < 16; j++) a += hid[j] * sW2[j * 2 + o];
        out[(size_t)gI * 2 + o] = a;
    }
}

extern "C" void kernel_launch(void* const* d_in, const int* in_sizes, int n_in,
                              void* d_out, int out_size, void* d_ws, size_t ws_size,
                              hipStream_t stream) {
    const float* x       = (const float*)d_in[0];
    const int*   ei      = (const int*)d_in[1];
    const float* eattr   = (const float*)d_in[2];
    const int*   batch   = (const int*)d_in[3];
    const float* node_w  = (const float*)d_in[4];
    const float* node_b  = (const float*)d_in[5];
    const float* edge_w  = (const float*)d_in[6];
    const float* edge_b  = (const float*)d_in[7];
    const float* conv_w1 = (const float*)d_in[8];
    const float* conv_b1 = (const float*)d_in[9];
    const float* conv_w2 = (const float*)d_in[10];
    const float* conv_b2 = (const float*)d_in[11];
    const float* bn_g    = (const float*)d_in[12];
    const float* bn_b    = (const float*)d_in[13];
    const float* lin1_w  = (const float*)d_in[14];
    const float* lin1_b  = (const float*)d_in[15];
    const float* lin2_w  = (const float*)d_in[16];
    const float* lin2_b  = (const float*)d_in[17];
    float* out = (float*)d_out;

    float4* packed = (float4*)d_ws;                        // 51.2 MB
    float4* buf1   = packed + N_EDGES;                     // 51.2 MB (CSR build only)
    float*  h      = (float*)(buf1 + N_EDGES);             // 12.8 MB
    float*  agg    = h + (size_t)N_NODES * 32;             // 12.8 MB (z in-place)
    __half* h16    = (__half*)(agg + (size_t)N_NODES * 32);// 6.4 MB
    int*    cmat   = (int*)(h16 + (size_t)N_NODES * 32);   // LALLOC ints
    int*    t1     = cmat + LALLOC;                        // 1280
    int*    offs   = t1 + 1280;                            // NPAD2+1
    int*    goff   = offs + NPAD2 + 1;                     // N_GRAPHS+1
    float*  stats  = (float*)(goff + N_GRAPHS + 1);        // 64
    float*  gsum   = stats + 64;                           // G*32
    float*  w1tp   = gsum + (size_t)N_GRAPHS * 32;         // 2*80*32
    float*  b1p    = w1tp + 2 * HPAD * 32;                 // 2*80
    float*  w2p    = b1p + 2 * HPAD;                       // 2*80*32

    int nb_nodes = (N_NODES + 255) / 256;
    int nb_vec   = (N_NODES * 8 + 255) / 256;

    hipMemsetAsync(cmat, 0, LALLOC * sizeof(int), stream);
    k_encode<<<nb_nodes, 256, 0, stream>>>(x, node_w, node_b, h, h16);
    k_prep<<<(2 * HPAD * 32 + 2 * HPAD + 255) / 256, 256, 0, stream>>>(
        conv_w1, conv_b1, conv_w2, w1tp, b1p, w2p);
    k_goff<<<(N_GRAPHS + 1 + 255) / 256, 256, 0, stream>>>(batch, goff);

    ksA<<<NBLKA, 256, 0, stream>>>(ei, cmat);
    ks1<<<NS1, 256, 0, stream>>>(cmat, t1);
    ks2<<<1, 256, 0, stream>>>(t1);
    ks3<<<NS1, 256, 0, stream>>>(cmat, t1);
    ksB<<<NBLKA, 256, 0, stream>>>(ei, eattr, cmat, buf1);
    ksC<<<NBKT, 1024, 0, stream>>>(cmat, buf1, packed, offs);

    for (int l = 0; l < 2; l++) {
        hipMemsetAsync(stats, 0, 64 * sizeof(float), stream);
        k_agg<<<N_NODES * 32 / 256, 256, 0, stream>>>(packed, offs, edge_w, edge_b, h16, agg);
        k_mlp<<<N_NODES * 8 / 256, 256, 0, stream>>>(h, agg, w1tp + l * HPAD * 32,
                                                     b1p + l * HPAD, w2p + l * HPAD * 32,
                                                     conv_b2 + l * 32);
        k_stats<<<256, 256, 0, stream>>>(agg, stats);
        k_bn<<<nb_vec, 256, 0, stream>>>(agg, h, h16, stats, bn_g + l * 32, bn_b + l * 32);
    }
    k_pool2<<<(N_GRAPHS + 3) / 4, 256, 0, stream>>>(h, goff, gsum);
    k_head<<<(N_GRAPHS + 255) / 256, 256, 0, stream>>>(gsum, goff, lin1_w, lin1_b, lin2_w, lin2_b, out);
}

// Round 18
// 475.106 us; speedup vs baseline: 1.3325x; 1.0394x over previous
//
#include <hip/hip_runtime.h>
#include <hip/hip_fp16.h>

#define N_NODES 100000
#define N_EDGES 3200000
#define N_GRAPHS 5000
#define BN_EPS 1e-5f
#define HPAD 80        // hidden 75 padded to 80
#define CHUNK 2048     // edges per bucket-sort block
#define NBLKA 1563     // ceil(N_EDGES / CHUNK)
#define NBKT 196       // buckets of 512 nodes (dst >> 9)
#define NPAD2 (NBKT * 512)   // 100352
#define NS1 1197       // ceil(NBKT*NBLKA / 256)
#define LALLOC (NS1 * 256)
#define VPT 5          // ceil(NS1 / 256) for ks2
#define W1S 36         // sW1 row stride (36 floats): oct*360 words -> 2-way bank alias (free)

// ---------- node encoder: h = x @ node_w + node_b (fp32 + fp16 mirror) ----------
__global__ void k_encode(const float* __restrict__ x, const float* __restrict__ W,
                         const float* __restrict__ b, float* __restrict__ h,
                         __half* __restrict__ h16) {
    __shared__ float sW[448];
    __shared__ float sb[32];
    for (int i = threadIdx.x; i < 448; i += 256) sW[i] = W[i];
    if (threadIdx.x < 32) sb[threadIdx.x] = b[threadIdx.x];
    __syncthreads();
    int n = blockIdx.x * 256 + threadIdx.x;
    if (n >= N_NODES) return;
    float xi[14];
#pragma unroll
    for (int k = 0; k < 14; k++) xi[k] = x[n * 14 + k];
    float4* hp = (float4*)(h + (size_t)n * 32);
    __half2* hq = (__half2*)(h16 + (size_t)n * 32);
#pragma unroll
    for (int q = 0; q < 8; q++) {
        float4 acc;
        float* ap = (float*)&acc;
#pragma unroll
        for (int i = 0; i < 4; i++) {
            int c = q * 4 + i;
            float a = sb[c];
#pragma unroll
            for (int k = 0; k < 14; k++) a += xi[k] * sW[k * 32 + c];
            ap[i] = a;
        }
        hp[q] = acc;
        hq[q * 2 + 0] = __floats2half2_rn(acc.x, acc.y);
        hq[q * 2 + 1] = __floats2half2_rn(acc.z, acc.w);
    }
}

// ---------- weight prep ----------
__global__ void k_prep(const float* __restrict__ W1, const float* __restrict__ b1,
                       const float* __restrict__ W2,
                       float* __restrict__ w1tp, float* __restrict__ b1p,
                       float* __restrict__ w2p) {
    int i = blockIdx.x * 256 + threadIdx.x;
    if (i < 2 * HPAD * 32) {
        int l = i / (HPAD * 32), r = i % (HPAD * 32);
        int j = r / 32, c = r % 32;
        w1tp[i] = (j < 75) ? W1[l * 2400 + c * 75 + j] : 0.f;
        w2p[i]  = (j < 75) ? W2[l * 2400 + j * 32 + c] : 0.f;
    } else if (i < 2 * HPAD * 32 + 2 * HPAD) {
        int k = i - 2 * HPAD * 32;
        int l = k / HPAD, j = k % HPAD;
        b1p[k] = (j < 75) ? b1[l * 75 + j] : 0.f;
    }
}

// ---------- bucket sort phase A: 196-bucket per-block histogram ----------
__global__ void __launch_bounds__(256) ksA(const int* __restrict__ ei, int* __restrict__ cmat) {
    __shared__ int lh[NBKT];
    if (threadIdx.x < NBKT) lh[threadIdx.x] = 0;
    __syncthreads();
    int b0 = blockIdx.x * CHUNK;
    for (int i = threadIdx.x; i < CHUNK; i += 256) {
        int e = b0 + i;
        if (e < N_EDGES) atomicAdd(&lh[ei[N_EDGES + e] >> 9], 1);
    }
    __syncthreads();
    if (threadIdx.x < NBKT) cmat[threadIdx.x * NBLKA + blockIdx.x] = lh[threadIdx.x];
}

// ---------- parallel exclusive scan of cmat ----------
__global__ void ks1(const int* __restrict__ a, int* __restrict__ bs) {
    __shared__ int s[256];
    int i = blockIdx.x * 256 + threadIdx.x;
    s[threadIdx.x] = a[i];
    __syncthreads();
    for (int o = 128; o > 0; o >>= 1) {
        if (threadIdx.x < o) s[threadIdx.x] += s[threadIdx.x + o];
        __syncthreads();
    }
    if (threadIdx.x == 0) bs[blockIdx.x] = s[0];
}

__global__ void ks2(int* __restrict__ bs) {
    __shared__ int s[256];
    int t = threadIdx.x;
    int v[VPT];
    int base = t * VPT, sum = 0;
#pragma unroll
    for (int k = 0; k < VPT; k++) {
        int idx = base + k;
        int x = (idx < NS1) ? bs[idx] : 0;
        v[k] = sum; sum += x;
    }
    s[t] = sum;
    __syncthreads();
    for (int o = 1; o < 256; o <<= 1) {
        int add = (t >= o) ? s[t - o] : 0;
        __syncthreads();
        s[t] += add;
        __syncthreads();
    }
    int excl = (t == 0) ? 0 : s[t - 1];
#pragma unroll
    for (int k = 0; k < VPT; k++) {
        int idx = base + k;
        if (idx < NS1) bs[idx] = excl + v[k];
    }
}

__global__ void ks3(int* __restrict__ a, const int* __restrict__ bs) {
    __shared__ int s[256];
    int t = threadIdx.x, i = blockIdx.x * 256 + t;
    int v = a[i];
    s[t] = v;
    __syncthreads();
    for (int o = 1; o < 256; o <<= 1) {
        int add = (t >= o) ? s[t - o] : 0;
        __syncthreads();
        s[t] += add;
        __syncthreads();
    }
    a[i] = s[t] - v + bs[blockIdx.x];
}

// ---------- phase B: per-block counting sort in LDS, then coalesced drain ----------
__global__ void __launch_bounds__(256) ksB(const int* __restrict__ ei, const float* __restrict__ ea,
                                           const int* __restrict__ cmat, float4* __restrict__ buf1) {
    __shared__ float4 rec[CHUNK];              // 32 KB sorted records
    __shared__ unsigned short sbkt[CHUNK];     // 4 KB bucket tag per rank
    __shared__ int lh[NBKT];                   // histogram -> cursor
    __shared__ int lex[NBKT];                  // local exclusive offsets
    __shared__ int gb[NBKT];                   // global base for (bucket, this block)
    __shared__ int sc[256];                    // scan temp
    int t = threadIdx.x;
    int b0 = blockIdx.x * CHUNK;
    int nval = min(CHUNK, N_EDGES - b0);
    if (t < NBKT) lh[t] = 0;
    __syncthreads();
    for (int i = t; i < nval; i += 256)
        atomicAdd(&lh[ei[N_EDGES + b0 + i] >> 9], 1);
    __syncthreads();
    sc[t] = (t < NBKT) ? lh[t] : 0;
    __syncthreads();
    for (int o = 1; o < 256; o <<= 1) {
        int add = (t >= o) ? sc[t - o] : 0;
        __syncthreads();
        sc[t] += add;
        __syncthreads();
    }
    if (t < NBKT) {
        lex[t] = sc[t] - lh[t];
        gb[t] = cmat[t * NBLKA + blockIdx.x];
        lh[t] = sc[t] - lh[t];
    }
    __syncthreads();
    for (int i = t; i < nval; i += 256) {
        int e = b0 + i;
        int src = ei[e], dst = ei[N_EDGES + e];
        float a0 = ea[(size_t)e * 3 + 0], a1 = ea[(size_t)e * 3 + 1], a2 = ea[(size_t)e * 3 + 2];
        int bkt = dst >> 9;
        int r = atomicAdd(&lh[bkt], 1);
        rec[r] = make_float4(a0, a1, a2, __int_as_float(src | ((dst & 511) << 17)));
        sbkt[r] = (unsigned short)bkt;
    }
    __syncthreads();
    for (int p = t; p < nval; p += 256) {
        int bkt = sbkt[p];
        buf1[gb[bkt] + (p - lex[bkt])] = rec[p];
    }
}

// ---------- phase C: per-512-node-bucket exact CSR (1024-thread blocks) ----------
__global__ void __launch_bounds__(1024) ksC(const int* __restrict__ cmat, const float4* __restrict__ buf1,
                                            float4* __restrict__ packed, int* __restrict__ offs) {
    __shared__ int cnt[512];
    __shared__ int sc[512];
    __shared__ int excl[513];
    int g = blockIdx.x, t = threadIdx.x;
    int bb = cmat[g * NBLKA];
    int be = (g == NBKT - 1) ? N_EDGES : cmat[(g + 1) * NBLKA];
    if (t < 512) cnt[t] = 0;
    __syncthreads();
    for (int j = bb + t; j < be; j += 1024) {
        int bits = __float_as_int(buf1[j].w);
        atomicAdd(&cnt[bits >> 17], 1);
    }
    __syncthreads();
    if (t < 512) sc[t] = cnt[t];
    __syncthreads();
    for (int o = 1; o < 512; o <<= 1) {
        int add = 0;
        if (t < 512 && t >= o) add = sc[t - o];
        __syncthreads();
        if (t < 512) sc[t] += add;
        __syncthreads();
    }
    if (t < 512) excl[t] = sc[t] - cnt[t];
    if (t == 511) excl[512] = sc[511];
    __syncthreads();
    if (t < 512) offs[g * 512 + t] = bb + excl[t];
    if (g == NBKT - 1 && t == 0) offs[NPAD2] = N_EDGES;
    if (t < 512) cnt[t] = 0;
    __syncthreads();
    for (int j = bb + t; j < be; j += 1024) {
        float4 r = buf1[j];
        int bits = __float_as_int(r.w);
        int dl = bits >> 17, src = bits & 0x1FFFF;
        int rank = atomicAdd(&cnt[dl], 1);
        packed[bb + excl[dl] + rank] = make_float4(r.x, r.y, r.z, __int_as_float(src));
    }
}

// ---------- pull aggregation: 32 threads/node, fp16 h-gather ----------
__global__ void __launch_bounds__(256) k_agg(const float4* __restrict__ packed,
                                             const int* __restrict__ offs,
                                             const float* __restrict__ eW, const float* __restrict__ eb,
                                             const __half* __restrict__ h16, float* __restrict__ agg) {
    int t = blockIdx.x * 256 + threadIdx.x;   // N_NODES*32 exact
    int n = t >> 5, s = t & 31;
    int q = s & 7, part = s >> 3;             // quad 0..7, edge-part 0..3
    int c0 = q * 4;
    float w0[4], w1[4], w2[4], bb4[4];
#pragma unroll
    for (int i = 0; i < 4; i++) {
        w0[i] = eW[c0 + i];
        w1[i] = eW[32 + c0 + i];
        w2[i] = eW[64 + c0 + i];
        bb4[i] = eb[c0 + i];
    }
    int beg = offs[n], end = offs[n + 1];
    float acc0[4] = {0.f, 0.f, 0.f, 0.f};
    float acc1[4] = {0.f, 0.f, 0.f, 0.f};
    int j = beg + part;
    for (; j + 4 < end; j += 8) {
        float4 pa = packed[j];
        float4 pb = packed[j + 4];
        float2 ra = *(const float2*)(h16 + (size_t)__float_as_int(pa.w) * 32 + c0);
        float2 rb = *(const float2*)(h16 + (size_t)__float_as_int(pb.w) * 32 + c0);
        float2 a01 = __half22float2(*(__half2*)&ra.x);
        float2 a23 = __half22float2(*(__half2*)&ra.y);
        float2 b01 = __half22float2(*(__half2*)&rb.x);
        float2 b23 = __half22float2(*(__half2*)&rb.y);
        float ha4[4] = {a01.x, a01.y, a23.x, a23.y};
        float hb4[4] = {b01.x, b01.y, b23.x, b23.y};
#pragma unroll
        for (int i = 0; i < 4; i++) {
            acc0[i] += fmaxf(ha4[i] + pa.x * w0[i] + pa.y * w1[i] + pa.z * w2[i] + bb4[i], 0.f);
            acc1[i] += fmaxf(hb4[i] + pb.x * w0[i] + pb.y * w1[i] + pb.z * w2[i] + bb4[i], 0.f);
        }
    }
    if (j < end) {
        float4 p = packed[j];
        float2 r = *(const float2*)(h16 + (size_t)__float_as_int(p.w) * 32 + c0);
        float2 a01 = __half22float2(*(__half2*)&r.x);
        float2 a23 = __half22float2(*(__half2*)&r.y);
        float hp4[4] = {a01.x, a01.y, a23.x, a23.y};
#pragma unroll
        for (int i = 0; i < 4; i++)
            acc0[i] += fmaxf(hp4[i] + p.x * w0[i] + p.y * w1[i] + p.z * w2[i] + bb4[i], 0.f);
    }
    float acc[4];
#pragma unroll
    for (int i = 0; i < 4; i++) {
        acc[i] = acc0[i] + acc1[i];
        acc[i] += __shfl_xor(acc[i], 8, 64);
        acc[i] += __shfl_xor(acc[i], 16, 64);
    }
    if (part == 0)
        *(float4*)(agg + (size_t)n * 32 + c0) = make_float4(acc[0], acc[1], acc[2], acc[3]);
}

// ---------- fused MLP: z = relu((h+agg)@W1+b1)@W2+b2, written over agg ----------
// Weights in LDS; sW1 rows padded to stride 36 so the 8 per-wave oct addresses
// alias banks only 2-way (free) instead of 8-way.
__global__ void __launch_bounds__(256, 4) k_mlp(const float* __restrict__ h, float* __restrict__ agg,
                                                const float* __restrict__ W1, const float* __restrict__ B1,
                                                const float* __restrict__ W2, const float* __restrict__ b2) {
    __shared__ float sW1[HPAD * W1S];  // [j(80)][c(32)] stride 36
    __shared__ float sW2[2560];        // [j(80)][c(32)]
    __shared__ float sB1[80];
    __shared__ float sb2[32];
    __shared__ float hidL[32 * 84];    // 4 waves * 8 nodes; stride 84
    for (int i = threadIdx.x; i < 2560; i += 256) {
        int j = i >> 5, c = i & 31;
        sW1[j * W1S + c] = W1[i];
        sW2[i] = W2[i];
    }
    if (threadIdx.x < 80) sB1[threadIdx.x] = B1[threadIdx.x];
    if (threadIdx.x < 32) sb2[threadIdx.x] = b2[threadIdx.x];
    __syncthreads();
    unsigned t = blockIdx.x * 256 + threadIdx.x;   // N_NODES*8 exact
    unsigned lane = threadIdx.x & 63;
    unsigned wv = threadIdx.x >> 6;
    unsigned oct = lane >> 3;
    unsigned nd = lane & 7;
    unsigned n = (t >> 6) * 8 + nd;
    const float4* hp = (const float4*)(h + (size_t)n * 32);
    const float4* ap = (const float4*)(agg + (size_t)n * 32);
    float zc[32];
#pragma unroll
    for (int q = 0; q < 8; q++) {
        float4 hv = hp[q], av = ap[q];
        zc[q * 4 + 0] = hv.x + av.x;
        zc[q * 4 + 1] = hv.y + av.y;
        zc[q * 4 + 2] = hv.z + av.z;
        zc[q * 4 + 3] = hv.w + av.w;
    }
    float hid[10];
#pragma unroll
    for (int i = 0; i < 10; i++) {
        int j = (int)oct * 10 + i;
        const float4* wp = (const float4*)(sW1 + j * W1S);
        float a0 = 0.f, a1 = 0.f, a2 = 0.f, a3 = 0.f;
#pragma unroll
        for (int q = 0; q < 8; q++) {
            float4 wv4 = wp[q];
            a0 += zc[q * 4 + 0] * wv4.x;
            a1 += zc[q * 4 + 1] * wv4.y;
            a2 += zc[q * 4 + 2] * wv4.z;
            a3 += zc[q * 4 + 3] * wv4.w;
        }
        hid[i] = fmaxf(sB1[j] + ((a0 + a1) + (a2 + a3)), 0.f);
    }
    float* hrow = &hidL[(wv * 8 + nd) * 84];
#pragma unroll
    for (int i = 0; i < 10; i++) hrow[oct * 10 + i] = hid[i];
    float4 zo = *(const float4*)(sb2 + oct * 4);
    const float4* hv4 = (const float4*)hrow;
#pragma unroll
    for (int k = 0; k < 20; k++) {
        float4 hv = hv4[k];
        const float* wr = sW2 + (k * 4) * 32 + oct * 4;
        float4 wa = *(const float4*)(wr);
        float4 wb = *(const float4*)(wr + 32);
        float4 wc = *(const float4*)(wr + 64);
        float4 wd = *(const float4*)(wr + 96);
        zo.x += hv.x * wa.x + hv.y * wb.x + hv.z * wc.x + hv.w * wd.x;
        zo.y += hv.x * wa.y + hv.y * wb.y + hv.z * wc.y + hv.w * wd.y;
        zo.z += hv.x * wa.z + hv.y * wb.z + hv.z * wc.z + hv.w * wd.z;
        zo.w += hv.x * wa.w + hv.y * wb.w + hv.z * wc.w + hv.w * wd.w;
    }
    *(float4*)(agg + (size_t)n * 32 + oct * 4) = zo;
}

// ---------- BN stats ----------
__global__ void __launch_bounds__(256) k_stats(const float* __restrict__ z, float* __restrict__ stats) {
    __shared__ float ls[4 * 64];
    int tid = threadIdx.x;
    int c = tid & 31;
    float s = 0.f, s2 = 0.f;
    for (int e = blockIdx.x * 256 + tid; e < N_NODES * 32; e += 256 * 256) {
        float v = z[e];
        s += v; s2 += v * v;
    }
    s += __shfl_down(s, 32, 64);
    s2 += __shfl_down(s2, 32, 64);
    int wave = tid >> 6, lane = tid & 63;
    if (lane < 32) { ls[wave * 64 + c] = s; ls[wave * 64 + 32 + c] = s2; }
    __syncthreads();
    if (tid < 64) {
        float a = ls[tid] + ls[64 + tid] + ls[128 + tid] + ls[192 + tid];
        atomicAdd(&stats[tid], a);
    }
}

// ---------- BN apply + relu (fp32 h + fp16 mirror) ----------
__global__ void k_bn(const float* __restrict__ z, float* __restrict__ h,
                     __half* __restrict__ h16,
                     const float* __restrict__ stats, const float* __restrict__ g,
                     const float* __restrict__ b) {
    int t = blockIdx.x * 256 + threadIdx.x;
    if (t >= N_NODES * 8) return;
    int q = t & 7;
    float4 zv = ((const float4*)z)[t];
    float* zp = (float*)&zv;
    float4 ov;
    float* op = (float*)&ov;
    const float invN = 1.0f / (float)N_NODES;
#pragma unroll
    for (int i = 0; i < 4; i++) {
        int c = q * 4 + i;
        float mu = stats[c] * invN;
        float var = stats[32 + c] * invN - mu * mu;
        float sc = g[c] / sqrtf(var + BN_EPS);
        op[i] = fmaxf((zp[i] - mu) * sc + b[c], 0.f);
    }
    ((float4*)h)[t] = ov;
    __half2 p0 = __floats2half2_rn(ov.x, ov.y);
    __half2 p1 = __floats2half2_rn(ov.z, ov.w);
    __half2* hq = (__half2*)(h16 + (size_t)t * 4);
    hq[0] = p0;
    hq[1] = p1;
}

// ---------- graph offsets (batch is sorted) ----------
__global__ void k_goff(const int* __restrict__ batch, int* __restrict__ goff) {
    int g = blockIdx.x * 256 + threadIdx.x;
    if (g > N_GRAPHS) return;
    int lo = 0, hi = N_NODES;
    while (lo < hi) {
        int mid = (lo + hi) >> 1;
        if (batch[mid] < g) lo = mid + 1; else hi = mid;
    }
    goff[g] = lo;
}

// ---------- mean-pool: one wave per graph ----------
__global__ void __launch_bounds__(256) k_pool2(const float* __restrict__ h, const int* __restrict__ goff,
                                               float* __restrict__ gsum) {
    int wid = threadIdx.x >> 6, lane = threadIdx.x & 63;
    int g = blockIdx.x * 4 + wid;
    if (g >= N_GRAPHS) return;
    int s = goff[g], e = goff[g + 1];
    int c = lane & 31, half = lane >> 5;
    float acc = 0.f;
    for (int n = s + half; n < e; n += 2) acc += h[(size_t)n * 32 + c];
    acc += __shfl_down(acc, 32, 64);
    if (lane < 32) gsum[(size_t)g * 32 + c] = acc;
}

__global__ void k_head(const float* __restrict__ gsum, const int* __restrict__ goff,
                       const float* __restrict__ W1, const float* __restrict__ b1,
                       const float* __restrict__ W2, const float* __restrict__ b2,
                       float* __restrict__ out) {
    __shared__ float sW1[512], sb1[16], sW2[32], sb2[2];
    for (int i = threadIdx.x; i < 512; i += 256) sW1[i] = W1[i];
    if (threadIdx.x < 16) sb1[threadIdx.x] = b1[threadIdx.x];
    if (threadIdx.x < 32) sW2[threadIdx.x] = W2[threadIdx.x];
    if (threadIdx.x < 2) sb2[threadIdx.x] = b2[threadIdx.x];
    __syncthreads();
    int gI = blockIdx.x * 256 + threadIdx.x;
    if (gI >= N_GRAPHS) return;
    float cnt = (float)(goff[gI + 1] - goff[gI]);
    float inv = 1.0f / fmaxf(cnt, 1.0f);
    float gx[32];
#pragma unroll
    for (int c = 0; c < 32; c++) gx[c] = gsum[(size_t)gI * 32 + c] * inv;
    float hid[16];
#pragma unroll
    for (int j = 0; j < 16; j++) {
        float a = sb1[j];
#pragma unroll
        for (int c = 0; c < 32; c++) a += gx[c] * sW1[c * 16 + j];
        hid[j] = fmaxf(a, 0.f);
    }
#pragma unroll
    for (int o = 0; o < 2; o++) {
        float a = sb2[o];
#pragma unroll
        for (int j = 0; j < 16; j++) a += hid[j] * sW2[j * 2 + o];
        out[(size_t)gI * 2 + o] = a;
    }
}

extern "C" void kernel_launch(void* const* d_in, const int* in_sizes, int n_in,
                              void* d_out, int out_size, void* d_ws, size_t ws_size,
                              hipStream_t stream) {
    const float* x       = (const float*)d_in[0];
    const int*   ei      = (const int*)d_in[1];
    const float* eattr   = (const float*)d_in[2];
    const int*   batch   = (const int*)d_in[3];
    const float* node_w  = (const float*)d_in[4];
    const float* node_b  = (const float*)d_in[5];
    const float* edge_w  = (const float*)d_in[6];
    const float* edge_b  = (const float*)d_in[7];
    const float* conv_w1 = (const float*)d_in[8];
    const float* conv_b1 = (const float*)d_in[9];
    const float* conv_w2 = (const float*)d_in[10];
    const float* conv_b2 = (const float*)d_in[11];
    const float* bn_g    = (const float*)d_in[12];
    const float* bn_b    = (const float*)d_in[13];
    const float* lin1_w  = (const float*)d_in[14];
    const float* lin1_b  = (const float*)d_in[15];
    const float* lin2_w  = (const float*)d_in[16];
    const float* lin2_b  = (const float*)d_in[17];
    float* out = (float*)d_out;

    float4* packed = (float4*)d_ws;                        // 51.2 MB
    float4* buf1   = packed + N_EDGES;                     // 51.2 MB (CSR build only)
    float*  h      = (float*)(buf1 + N_EDGES);             // 12.8 MB
    float*  agg    = h + (size_t)N_NODES * 32;             // 12.8 MB (z in-place)
    __half* h16    = (__half*)(agg + (size_t)N_NODES * 32);// 6.4 MB
    int*    cmat   = (int*)(h16 + (size_t)N_NODES * 32);   // LALLOC ints
    int*    t1     = cmat + LALLOC;                        // 1280
    int*    offs   = t1 + 1280;                            // NPAD2+1
    int*    goff   = offs + NPAD2 + 1;                     // N_GRAPHS+1
    float*  stats  = (float*)(goff + N_GRAPHS + 1);        // 64
    float*  gsum   = stats + 64;                           // G*32
    float*  w1tp   = gsum + (size_t)N_GRAPHS * 32;         // 2*80*32
    float*  b1p    = w1tp + 2 * HPAD * 32;                 // 2*80
    float*  w2p    = b1p + 2 * HPAD;                       // 2*80*32

    int nb_nodes = (N_NODES + 255) / 256;
    int nb_vec   = (N_NODES * 8 + 255) / 256;

    hipMemsetAsync(cmat, 0, LALLOC * sizeof(int), stream);
    k_encode<<<nb_nodes, 256, 0, stream>>>(x, node_w, node_b, h, h16);
    k_prep<<<(2 * HPAD * 32 + 2 * HPAD + 255) / 256, 256, 0, stream>>>(
        conv_w1, conv_b1, conv_w2, w1tp, b1p, w2p);
    k_goff<<<(N_GRAPHS + 1 + 255) / 256, 256, 0, stream>>>(batch, goff);

    ksA<<<NBLKA, 256, 0, stream>>>(ei, cmat);
    ks1<<<NS1, 256, 0, stream>>>(cmat, t1);
    ks2<<<1, 256, 0, stream>>>(t1);
    ks3<<<NS1, 256, 0, stream>>>(cmat, t1);
    ksB<<<NBLKA, 256, 0, stream>>>(ei, eattr, cmat, buf1);
    ksC<<<NBKT, 1024, 0, stream>>>(cmat, buf1, packed, offs);

    for (int l = 0; l < 2; l++) {
        hipMemsetAsync(stats, 0, 64 * sizeof(float), stream);
        k_agg<<<N_NODES * 32 / 256, 256, 0, stream>>>(packed, offs, edge_w, edge_b, h16, agg);
        k_mlp<<<N_NODES * 8 / 256, 256, 0, stream>>>(h, agg, w1tp + l * HPAD * 32,
                                                     b1p + l * HPAD, w2p + l * HPAD * 32,
                                                     conv_b2 + l * 32);
        k_stats<<<256, 256, 0, stream>>>(agg, stats);
        k_bn<<<nb_vec, 256, 0, stream>>>(agg, h, h16, stats, bn_g + l * 32, bn_b + l * 32);
    }
    k_pool2<<<(N_GRAPHS + 3) / 4, 256, 0, stream>>>(h, goff, gsum);
    k_head<<<(N_GRAPHS + 255) / 256, 256, 0, stream>>>(gsum, goff, lin1_w, lin1_b, lin2_w, lin2_b, out);
}

// Round 19
// 468.517 us; speedup vs baseline: 1.3513x; 1.0141x over previous
//
#include <hip/hip_runtime.h>
#include <hip/hip_fp16.h>

#define N_NODES 100000
#define N_EDGES 3200000
#define N_GRAPHS 5000
#define BN_EPS 1e-5f
#define HPAD 80        // hidden 75 padded to 80
#define CHUNK 2048     // edges per bucket-sort block
#define NBLKA 1563     // ceil(N_EDGES / CHUNK)
#define NBKT 196       // buckets of 512 nodes (dst >> 9)
#define NPAD2 (NBKT * 512)   // 100352
#define NS1 1197       // ceil(NBKT*NBLKA / 256)
#define LALLOC (NS1 * 256)
#define VPT 5          // ceil(NS1 / 256) for ks2
#define W1S 36         // sW1 row stride: 2-way bank alias only (free)

// ---------- node encoder: h = x @ node_w + node_b (fp32 + fp16 mirror) ----------
__global__ void k_encode(const float* __restrict__ x, const float* __restrict__ W,
                         const float* __restrict__ b, float* __restrict__ h,
                         __half* __restrict__ h16) {
    __shared__ float sW[448];
    __shared__ float sb[32];
    for (int i = threadIdx.x; i < 448; i += 256) sW[i] = W[i];
    if (threadIdx.x < 32) sb[threadIdx.x] = b[threadIdx.x];
    __syncthreads();
    int n = blockIdx.x * 256 + threadIdx.x;
    if (n >= N_NODES) return;
    float xi[14];
#pragma unroll
    for (int k = 0; k < 14; k++) xi[k] = x[n * 14 + k];
    float4* hp = (float4*)(h + (size_t)n * 32);
    __half2* hq = (__half2*)(h16 + (size_t)n * 32);
#pragma unroll
    for (int q = 0; q < 8; q++) {
        float4 acc;
        float* ap = (float*)&acc;
#pragma unroll
        for (int i = 0; i < 4; i++) {
            int c = q * 4 + i;
            float a = sb[c];
#pragma unroll
            for (int k = 0; k < 14; k++) a += xi[k] * sW[k * 32 + c];
            ap[i] = a;
        }
        hp[q] = acc;
        hq[q * 2 + 0] = __floats2half2_rn(acc.x, acc.y);
        hq[q * 2 + 1] = __floats2half2_rn(acc.z, acc.w);
    }
}

// ---------- weight prep ----------
__global__ void k_prep(const float* __restrict__ W1, const float* __restrict__ b1,
                       const float* __restrict__ W2,
                       float* __restrict__ w1tp, float* __restrict__ b1p,
                       float* __restrict__ w2p) {
    int i = blockIdx.x * 256 + threadIdx.x;
    if (i < 2 * HPAD * 32) {
        int l = i / (HPAD * 32), r = i % (HPAD * 32);
        int j = r / 32, c = r % 32;
        w1tp[i] = (j < 75) ? W1[l * 2400 + c * 75 + j] : 0.f;
        w2p[i]  = (j < 75) ? W2[l * 2400 + j * 32 + c] : 0.f;
    } else if (i < 2 * HPAD * 32 + 2 * HPAD) {
        int k = i - 2 * HPAD * 32;
        int l = k / HPAD, j = k % HPAD;
        b1p[k] = (j < 75) ? b1[l * 75 + j] : 0.f;
    }
}

// ---------- bucket sort phase A ----------
__global__ void __launch_bounds__(256) ksA(const int* __restrict__ ei, int* __restrict__ cmat) {
    __shared__ int lh[NBKT];
    if (threadIdx.x < NBKT) lh[threadIdx.x] = 0;
    __syncthreads();
    int b0 = blockIdx.x * CHUNK;
    for (int i = threadIdx.x; i < CHUNK; i += 256) {
        int e = b0 + i;
        if (e < N_EDGES) atomicAdd(&lh[ei[N_EDGES + e] >> 9], 1);
    }
    __syncthreads();
    if (threadIdx.x < NBKT) cmat[threadIdx.x * NBLKA + blockIdx.x] = lh[threadIdx.x];
}

// ---------- parallel exclusive scan of cmat ----------
__global__ void ks1(const int* __restrict__ a, int* __restrict__ bs) {
    __shared__ int s[256];
    int i = blockIdx.x * 256 + threadIdx.x;
    s[threadIdx.x] = a[i];
    __syncthreads();
    for (int o = 128; o > 0; o >>= 1) {
        if (threadIdx.x < o) s[threadIdx.x] += s[threadIdx.x + o];
        __syncthreads();
    }
    if (threadIdx.x == 0) bs[blockIdx.x] = s[0];
}

__global__ void ks2(int* __restrict__ bs) {
    __shared__ int s[256];
    int t = threadIdx.x;
    int v[VPT];
    int base = t * VPT, sum = 0;
#pragma unroll
    for (int k = 0; k < VPT; k++) {
        int idx = base + k;
        int x = (idx < NS1) ? bs[idx] : 0;
        v[k] = sum; sum += x;
    }
    s[t] = sum;
    __syncthreads();
    for (int o = 1; o < 256; o <<= 1) {
        int add = (t >= o) ? s[t - o] : 0;
        __syncthreads();
        s[t] += add;
        __syncthreads();
    }
    int excl = (t == 0) ? 0 : s[t - 1];
#pragma unroll
    for (int k = 0; k < VPT; k++) {
        int idx = base + k;
        if (idx < NS1) bs[idx] = excl + v[k];
    }
}

__global__ void ks3(int* __restrict__ a, const int* __restrict__ bs) {
    __shared__ int s[256];
    int t = threadIdx.x, i = blockIdx.x * 256 + t;
    int v = a[i];
    s[t] = v;
    __syncthreads();
    for (int o = 1; o < 256; o <<= 1) {
        int add = (t >= o) ? s[t - o] : 0;
        __syncthreads();
        s[t] += add;
        __syncthreads();
    }
    a[i] = s[t] - v + bs[blockIdx.x];
}

// ---------- phase B: per-block counting sort in LDS, then coalesced drain ----------
__global__ void __launch_bounds__(256) ksB(const int* __restrict__ ei, const float* __restrict__ ea,
                                           const int* __restrict__ cmat, float4* __restrict__ buf1) {
    __shared__ float4 rec[CHUNK];
    __shared__ unsigned short sbkt[CHUNK];
    __shared__ int lh[NBKT];
    __shared__ int lex[NBKT];
    __shared__ int gb[NBKT];
    __shared__ int sc[256];
    int t = threadIdx.x;
    int b0 = blockIdx.x * CHUNK;
    int nval = min(CHUNK, N_EDGES - b0);
    if (t < NBKT) lh[t] = 0;
    __syncthreads();
    for (int i = t; i < nval; i += 256)
        atomicAdd(&lh[ei[N_EDGES + b0 + i] >> 9], 1);
    __syncthreads();
    sc[t] = (t < NBKT) ? lh[t] : 0;
    __syncthreads();
    for (int o = 1; o < 256; o <<= 1) {
        int add = (t >= o) ? sc[t - o] : 0;
        __syncthreads();
        sc[t] += add;
        __syncthreads();
    }
    if (t < NBKT) {
        lex[t] = sc[t] - lh[t];
        gb[t] = cmat[t * NBLKA + blockIdx.x];
        lh[t] = sc[t] - lh[t];
    }
    __syncthreads();
    for (int i = t; i < nval; i += 256) {
        int e = b0 + i;
        int src = ei[e], dst = ei[N_EDGES + e];
        float a0 = ea[(size_t)e * 3 + 0], a1 = ea[(size_t)e * 3 + 1], a2 = ea[(size_t)e * 3 + 2];
        int bkt = dst >> 9;
        int r = atomicAdd(&lh[bkt], 1);
        rec[r] = make_float4(a0, a1, a2, __int_as_float(src | ((dst & 511) << 17)));
        sbkt[r] = (unsigned short)bkt;
    }
    __syncthreads();
    for (int p = t; p < nval; p += 256) {
        int bkt = sbkt[p];
        buf1[gb[bkt] + (p - lex[bkt])] = rec[p];
    }
}

// ---------- phase C: per-512-node-bucket exact CSR ----------
__global__ void __launch_bounds__(1024) ksC(const int* __restrict__ cmat, const float4* __restrict__ buf1,
                                            float4* __restrict__ packed, int* __restrict__ offs) {
    __shared__ int cnt[512];
    __shared__ int sc[512];
    __shared__ int excl[513];
    int g = blockIdx.x, t = threadIdx.x;
    int bb = cmat[g * NBLKA];
    int be = (g == NBKT - 1) ? N_EDGES : cmat[(g + 1) * NBLKA];
    if (t < 512) cnt[t] = 0;
    __syncthreads();
    for (int j = bb + t; j < be; j += 1024) {
        int bits = __float_as_int(buf1[j].w);
        atomicAdd(&cnt[bits >> 17], 1);
    }
    __syncthreads();
    if (t < 512) sc[t] = cnt[t];
    __syncthreads();
    for (int o = 1; o < 512; o <<= 1) {
        int add = 0;
        if (t < 512 && t >= o) add = sc[t - o];
        __syncthreads();
        if (t < 512) sc[t] += add;
        __syncthreads();
    }
    if (t < 512) excl[t] = sc[t] - cnt[t];
    if (t == 511) excl[512] = sc[511];
    __syncthreads();
    if (t < 512) offs[g * 512 + t] = bb + excl[t];
    if (g == NBKT - 1 && t == 0) offs[NPAD2] = N_EDGES;
    if (t < 512) cnt[t] = 0;
    __syncthreads();
    for (int j = bb + t; j < be; j += 1024) {
        float4 r = buf1[j];
        int bits = __float_as_int(r.w);
        int dl = bits >> 17, src = bits & 0x1FFFF;
        int rank = atomicAdd(&cnt[dl], 1);
        packed[bb + excl[dl] + rank] = make_float4(r.x, r.y, r.z, __int_as_float(src));
    }
}

// ---------- pull aggregation: 32 threads/node, fp16 gather; writes zin = h + agg ----------
__global__ void __launch_bounds__(256) k_agg(const float4* __restrict__ packed,
                                             const int* __restrict__ offs,
                                             const float* __restrict__ eW, const float* __restrict__ eb,
                                             const __half* __restrict__ h16,
                                             const float* __restrict__ h, float* __restrict__ zin) {
    int t = blockIdx.x * 256 + threadIdx.x;   // N_NODES*32 exact
    int n = t >> 5, s = t & 31;
    int q = s & 7, part = s >> 3;
    int c0 = q * 4;
    float w0[4], w1[4], w2[4], bb4[4];
#pragma unroll
    for (int i = 0; i < 4; i++) {
        w0[i] = eW[c0 + i];
        w1[i] = eW[32 + c0 + i];
        w2[i] = eW[64 + c0 + i];
        bb4[i] = eb[c0 + i];
    }
    int beg = offs[n], end = offs[n + 1];
    float acc0[4] = {0.f, 0.f, 0.f, 0.f};
    float acc1[4] = {0.f, 0.f, 0.f, 0.f};
    int j = beg + part;
    for (; j + 4 < end; j += 8) {
        float4 pa = packed[j];
        float4 pb = packed[j + 4];
        float2 ra = *(const float2*)(h16 + (size_t)__float_as_int(pa.w) * 32 + c0);
        float2 rb = *(const float2*)(h16 + (size_t)__float_as_int(pb.w) * 32 + c0);
        float2 a01 = __half22float2(*(__half2*)&ra.x);
        float2 a23 = __half22float2(*(__half2*)&ra.y);
        float2 b01 = __half22float2(*(__half2*)&rb.x);
        float2 b23 = __half22float2(*(__half2*)&rb.y);
        float ha4[4] = {a01.x, a01.y, a23.x, a23.y};
        float hb4[4] = {b01.x, b01.y, b23.x, b23.y};
#pragma unroll
        for (int i = 0; i < 4; i++) {
            acc0[i] += fmaxf(ha4[i] + pa.x * w0[i] + pa.y * w1[i] + pa.z * w2[i] + bb4[i], 0.f);
            acc1[i] += fmaxf(hb4[i] + pb.x * w0[i] + pb.y * w1[i] + pb.z * w2[i] + bb4[i], 0.f);
        }
    }
    if (j < end) {
        float4 p = packed[j];
        float2 r = *(const float2*)(h16 + (size_t)__float_as_int(p.w) * 32 + c0);
        float2 a01 = __half22float2(*(__half2*)&r.x);
        float2 a23 = __half22float2(*(__half2*)&r.y);
        float hp4[4] = {a01.x, a01.y, a23.x, a23.y};
#pragma unroll
        for (int i = 0; i < 4; i++)
            acc0[i] += fmaxf(hp4[i] + p.x * w0[i] + p.y * w1[i] + p.z * w2[i] + bb4[i], 0.f);
    }
    float acc[4];
#pragma unroll
    for (int i = 0; i < 4; i++) {
        acc[i] = acc0[i] + acc1[i];
        acc[i] += __shfl_xor(acc[i], 8, 64);
        acc[i] += __shfl_xor(acc[i], 16, 64);
    }
    if (part == 0) {
        float4 hq = *(const float4*)(h + (size_t)n * 32 + c0);   // coalesced, L2-warm
        *(float4*)(zin + (size_t)n * 32 + c0) =
            make_float4(acc[0] + hq.x, acc[1] + hq.y, acc[2] + hq.z, acc[3] + hq.w);
    }
}

// ---------- fused MLP: z = relu(zin@W1+b1)@W2+b2, written over zin ----------
__global__ void __launch_bounds__(256, 4) k_mlp(float* __restrict__ zio,
                                                const float* __restrict__ W1, const float* __restrict__ B1,
                                                const float* __restrict__ W2, const float* __restrict__ b2) {
    __shared__ float sW1[HPAD * W1S];  // stride 36 (2-way bank alias = free)
    __shared__ float sW2[2560];
    __shared__ float sB1[80];
    __shared__ float sb2[32];
    __shared__ float hidL[32 * 84];
    for (int i = threadIdx.x; i < 2560; i += 256) {
        int j = i >> 5, c = i & 31;
        sW1[j * W1S + c] = W1[i];
        sW2[i] = W2[i];
    }
    if (threadIdx.x < 80) sB1[threadIdx.x] = B1[threadIdx.x];
    if (threadIdx.x < 32) sb2[threadIdx.x] = b2[threadIdx.x];
    __syncthreads();
    unsigned t = blockIdx.x * 256 + threadIdx.x;
    unsigned lane = threadIdx.x & 63;
    unsigned wv = threadIdx.x >> 6;
    unsigned oct = lane >> 3;
    unsigned nd = lane & 7;
    unsigned n = (t >> 6) * 8 + nd;
    const float4* ap = (const float4*)(zio + (size_t)n * 32);
    float zc[32];
#pragma unroll
    for (int q = 0; q < 8; q++) {
        float4 av = ap[q];
        zc[q * 4 + 0] = av.x;
        zc[q * 4 + 1] = av.y;
        zc[q * 4 + 2] = av.z;
        zc[q * 4 + 3] = av.w;
    }
    float hid[10];
#pragma unroll
    for (int i = 0; i < 10; i++) {
        int j = (int)oct * 10 + i;
        const float4* wp = (const float4*)(sW1 + j * W1S);
        float a0 = 0.f, a1 = 0.f, a2 = 0.f, a3 = 0.f;
#pragma unroll
        for (int q = 0; q < 8; q++) {
            float4 wv4 = wp[q];
            a0 += zc[q * 4 + 0] * wv4.x;
            a1 += zc[q * 4 + 1] * wv4.y;
            a2 += zc[q * 4 + 2] * wv4.z;
            a3 += zc[q * 4 + 3] * wv4.w;
        }
        hid[i] = fmaxf(sB1[j] + ((a0 + a1) + (a2 + a3)), 0.f);
    }
    float* hrow = &hidL[(wv * 8 + nd) * 84];
#pragma unroll
    for (int i = 0; i < 10; i++) hrow[oct * 10 + i] = hid[i];
    float4 zo = *(const float4*)(sb2 + oct * 4);
    const float4* hv4 = (const float4*)hrow;
#pragma unroll
    for (int k = 0; k < 20; k++) {
        float4 hv = hv4[k];
        const float* wr = sW2 + (k * 4) * 32 + oct * 4;
        float4 wa = *(const float4*)(wr);
        float4 wb = *(const float4*)(wr + 32);
        float4 wc = *(const float4*)(wr + 64);
        float4 wd = *(const float4*)(wr + 96);
        zo.x += hv.x * wa.x + hv.y * wb.x + hv.z * wc.x + hv.w * wd.x;
        zo.y += hv.x * wa.y + hv.y * wb.y + hv.z * wc.y + hv.w * wd.y;
        zo.z += hv.x * wa.z + hv.y * wb.z + hv.z * wc.z + hv.w * wd.z;
        zo.w += hv.x * wa.w + hv.y * wb.w + hv.z * wc.w + hv.w * wd.w;
    }
    *(float4*)(zio + (size_t)n * 32 + oct * 4) = zo;
}

// ---------- BN stats ----------
__global__ void __launch_bounds__(256) k_stats(const float* __restrict__ z, float* __restrict__ stats) {
    __shared__ float ls[4 * 64];
    int tid = threadIdx.x;
    int c = tid & 31;
    float s = 0.f, s2 = 0.f;
    for (int e = blockIdx.x * 256 + tid; e < N_NODES * 32; e += 256 * 256) {
        float v = z[e];
        s += v; s2 += v * v;
    }
    s += __shfl_down(s, 32, 64);
    s2 += __shfl_down(s2, 32, 64);
    int wave = tid >> 6, lane = tid & 63;
    if (lane < 32) { ls[wave * 64 + c] = s; ls[wave * 64 + 32 + c] = s2; }
    __syncthreads();
    if (tid < 64) {
        float a = ls[tid] + ls[64 + tid] + ls[128 + tid] + ls[192 + tid];
        atomicAdd(&stats[tid], a);
    }
}

// ---------- BN apply + relu (fp32 h + fp16 mirror) ----------
__global__ void k_bn(const float* __restrict__ z, float* __restrict__ h,
                     __half* __restrict__ h16,
                     const float* __restrict__ stats, const float* __restrict__ g,
                     const float* __restrict__ b) {
    int t = blockIdx.x * 256 + threadIdx.x;
    if (t >= N_NODES * 8) return;
    int q = t & 7;
    float4 zv = ((const float4*)z)[t];
    float* zp = (float*)&zv;
    float4 ov;
    float* op = (float*)&ov;
    const float invN = 1.0f / (float)N_NODES;
#pragma unroll
    for (int i = 0; i < 4; i++) {
        int c = q * 4 + i;
        float mu = stats[c] * invN;
        float var = stats[32 + c] * invN - mu * mu;
        float sc = g[c] / sqrtf(var + BN_EPS);
        op[i] = fmaxf((zp[i] - mu) * sc + b[c], 0.f);
    }
    ((float4*)h)[t] = ov;
    __half2 p0 = __floats2half2_rn(ov.x, ov.y);
    __half2 p1 = __floats2half2_rn(ov.z, ov.w);
    __half2* hq = (__half2*)(h16 + (size_t)t * 4);
    hq[0] = p0;
    hq[1] = p1;
}

// ---------- graph offsets (batch is sorted) ----------
__global__ void k_goff(const int* __restrict__ batch, int* __restrict__ goff) {
    int g = blockIdx.x * 256 + threadIdx.x;
    if (g > N_GRAPHS) return;
    int lo = 0, hi = N_NODES;
    while (lo < hi) {
        int mid = (lo + hi) >> 1;
        if (batch[mid] < g) lo = mid + 1; else hi = mid;
    }
    goff[g] = lo;
}

// ---------- mean-pool: one wave per graph ----------
__global__ void __launch_bounds__(256) k_pool2(const float* __restrict__ h, const int* __restrict__ goff,
                                               float* __restrict__ gsum) {
    int wid = threadIdx.x >> 6, lane = threadIdx.x & 63;
    int g = blockIdx.x * 4 + wid;
    if (g >= N_GRAPHS) return;
    int s = goff[g], e = goff[g + 1];
    int c = lane & 31, half = lane >> 5;
    float acc = 0.f;
    for (int n = s + half; n < e; n += 2) acc += h[(size_t)n * 32 + c];
    acc += __shfl_down(acc, 32, 64);
    if (lane < 32) gsum[(size_t)g * 32 + c] = acc;
}

__global__ void k_head(const float* __restrict__ gsum, const int* __restrict__ goff,
                       const float* __restrict__ W1, const float* __restrict__ b1,
                       const float* __restrict__ W2, const float* __restrict__ b2,
                       float* __restrict__ out) {
    __shared__ float sW1[512], sb1[16], sW2[32], sb2[2];
    for (int i = threadIdx.x; i < 512; i += 256) sW1[i] = W1[i];
    if (threadIdx.x < 16) sb1[threadIdx.x] = b1[threadIdx.x];
    if (threadIdx.x < 32) sW2[threadIdx.x] = W2[threadIdx.x];
    if (threadIdx.x < 2) sb2[threadIdx.x] = b2[threadIdx.x];
    __syncthreads();
    int gI = blockIdx.x * 256 + threadIdx.x;
    if (gI >= N_GRAPHS) return;
    float cnt = (float)(goff[gI + 1] - goff[gI]);
    float inv = 1.0f / fmaxf(cnt, 1.0f);
    float gx[32];
#pragma unroll
    for (int c = 0; c < 32; c++) gx[c] = gsum[(size_t)gI * 32 + c] * inv;
    float hid[16];
#pragma unroll
    for (int j = 0; j < 16; j++) {
        float a = sb1[j];
#pragma unroll
        for (int c = 0; c < 32; c++) a += gx[c] * sW1[c * 16 + j];
        hid[j] = fmaxf(a, 0.f);
    }
#pragma unroll
    for (int o = 0; o < 2; o++) {
        float a = sb2[o];
#pragma unroll
        for (int j = 0; j < 16; j++) a += hid[j] * sW2[j * 2 + o];
        out[(size_t)gI * 2 + o] = a;
    }
}

extern "C" void kernel_launch(void* const* d_in, const int* in_sizes, int n_in,
                              void* d_out, int out_size, void* d_ws, size_t ws_size,
                              hipStream_t stream) {
    const float* x       = (const float*)d_in[0];
    const int*   ei      = (const int*)d_in[1];
    const float* eattr   = (const float*)d_in[2];
    const int*   batch   = (const int*)d_in[3];
    const float* node_w  = (const float*)d_in[4];
    const float* node_b  = (const float*)d_in[5];
    const float* edge_w  = (const float*)d_in[6];
    const float* edge_b  = (const float*)d_in[7];
    const float* conv_w1 = (const float*)d_in[8];
    const float* conv_b1 = (const float*)d_in[9];
    const float* conv_w2 = (const float*)d_in[10];
    const float* conv_b2 = (const float*)d_in[11];
    const float* bn_g    = (const float*)d_in[12];
    const float* bn_b    = (const float*)d_in[13];
    const float* lin1_w  = (const float*)d_in[14];
    const float* lin1_b  = (const float*)d_in[15];
    const float* lin2_w  = (const float*)d_in[16];
    const float* lin2_b  = (const float*)d_in[17];
    float* out = (float*)d_out;

    float4* packed = (float4*)d_ws;                        // 51.2 MB
    float4* buf1   = packed + N_EDGES;                     // 51.2 MB (CSR build only)
    float*  h      = (float*)(buf1 + N_EDGES);             // 12.8 MB
    float*  agg    = h + (size_t)N_NODES * 32;             // 12.8 MB (zin / z in-place)
    __half* h16    = (__half*)(agg + (size_t)N_NODES * 32);// 6.4 MB
    int*    cmat   = (int*)(h16 + (size_t)N_NODES * 32);   // LALLOC ints
    int*    t1     = cmat + LALLOC;                        // 1280
    int*    offs   = t1 + 1280;                            // NPAD2+1
    int*    goff   = offs + NPAD2 + 1;                     // N_GRAPHS+1
    float*  stats  = (float*)(goff + N_GRAPHS + 1);        // 64
    float*  gsum   = stats + 64;                           // G*32
    float*  w1tp   = gsum + (size_t)N_GRAPHS * 32;         // 2*80*32
    float*  b1p    = w1tp + 2 * HPAD * 32;                 // 2*80
    float*  w2p    = b1p + 2 * HPAD;                       // 2*80*32

    int nb_nodes = (N_NODES + 255) / 256;
    int nb_vec   = (N_NODES * 8 + 255) / 256;

    hipMemsetAsync(cmat, 0, LALLOC * sizeof(int), stream);
    k_encode<<<nb_nodes, 256, 0, stream>>>(x, node_w, node_b, h, h16);
    k_prep<<<(2 * HPAD * 32 + 2 * HPAD + 255) / 256, 256, 0, stream>>>(
        conv_w1, conv_b1, conv_w2, w1tp, b1p, w2p);
    k_goff<<<(N_GRAPHS + 1 + 255) / 256, 256, 0, stream>>>(batch, goff);

    ksA<<<NBLKA, 256, 0, stream>>>(ei, cmat);
    ks1<<<NS1, 256, 0, stream>>>(cmat, t1);
    ks2<<<1, 256, 0, stream>>>(t1);
    ks3<<<NS1, 256, 0, stream>>>(cmat, t1);
    ksB<<<NBLKA, 256, 0, stream>>>(ei, eattr, cmat, buf1);
    ksC<<<NBKT, 1024, 0, stream>>>(cmat, buf1, packed, offs);

    for (int l = 0; l < 2; l++) {
        hipMemsetAsync(stats, 0, 64 * sizeof(float), stream);
        k_agg<<<N_NODES * 32 / 256, 256, 0, stream>>>(packed, offs, edge_w, edge_b, h16, h, agg);
        k_mlp<<<N_NODES * 8 / 256, 256, 0, stream>>>(agg, w1tp + l * HPAD * 32,
                                                     b1p + l * HPAD, w2p + l * HPAD * 32,
                                                     conv_b2 + l * 32);
        k_stats<<<256, 256, 0, stream>>>(agg, stats);
        k_bn<<<nb_vec, 256, 0, stream>>>(agg, h, h16, stats, bn_g + l * 32, bn_b + l * 32);
    }
    k_pool2<<<(N_GRAPHS + 3) / 4, 256, 0, stream>>>(h, goff, gsum);
    k_head<<<(N_GRAPHS + 255) / 256, 256, 0, stream>>>(gsum, goff, lin1_w, lin1_b, lin2_w, lin2_b, out);
}